// Round 1
// baseline (886.008 us; speedup 1.0000x reference)
//
#include <hip/hip_runtime.h>
#include <stdint.h>

// ---------------------------------------------------------------------------
// Problem constants (from reference)
// ---------------------------------------------------------------------------
#define EMB   256
#define HEADS 8
#define KMIX  8     // K in reference
#define GADD  2
#define RADD  2
#define REGION 64
#define STRIDE 32
#define BB    4
#define TT    4096
#define TP    128          // TT/STRIDE
#define VS    48           // KMIX*(2+GADD+RADD)
#define HID   1024         // 4*EMB
#define NQ    2048         // EMB*HEADS

// RNG mode: 1 = jax_threefry_partitionable (modern JAX default), 0 = original
#define RNG_PARTITIONABLE 1

// ---------------------------------------------------------------------------
// Threefry-2x32 block (JAX exact)
// ---------------------------------------------------------------------------
__device__ __forceinline__ uint32_t rotl32(uint32_t x, int d) {
  return (x << d) | (x >> (32 - d));
}

__device__ __forceinline__ void tf2x32(uint32_t k0, uint32_t k1,
                                       uint32_t x0, uint32_t x1,
                                       uint32_t& o0, uint32_t& o1) {
  uint32_t ks2 = k0 ^ k1 ^ 0x1BD11BDAu;
  x0 += k0; x1 += k1;
#define TFR(r) { x0 += x1; x1 = rotl32(x1, r); x1 ^= x0; }
  TFR(13) TFR(15) TFR(26) TFR(6)
  x0 += k1; x1 += ks2 + 1u;
  TFR(17) TFR(29) TFR(16) TFR(24)
  x0 += ks2; x1 += k0 + 2u;
  TFR(13) TFR(15) TFR(26) TFR(6)
  x0 += k0; x1 += k1 + 3u;
  TFR(17) TFR(29) TFR(16) TFR(24)
  x0 += k1; x1 += ks2 + 4u;
  TFR(13) TFR(15) TFR(26) TFR(6)
  x0 += ks2; x1 += k0 + 5u;
#undef TFR
  o0 = x0; o1 = x1;
}

// grand[8192]: randint(kg,(B,TP,K,GADD),0,4096)  -> only lower-bits stream matters
// rrand[8192]: randint(kr,(B,TP,K,RADD),0,64)
__global__ void rand_kernel(int* __restrict__ grand, int* __restrict__ rrand) {
  int i = blockIdx.x * blockDim.x + threadIdx.x;
#if RNG_PARTITIONABLE
  // key(42) = (0,42). foldlike split: child_i = block(key,(0,i))
  uint32_t kg0, kg1, kr0, kr1;
  tf2x32(0u, 42u, 0u, 0u, kg0, kg1);   // kg
  tf2x32(0u, 42u, 0u, 1u, kr0, kr1);   // kr
  uint32_t g2k0, g2k1, r2k0, r2k1;     // k2 = second child (lower-bits key)
  tf2x32(kg0, kg1, 0u, 1u, g2k0, g2k1);
  tf2x32(kr0, kr1, 0u, 1u, r2k0, r2k1);
  if (i < BB * TP * KMIX * GADD) {
    uint32_t o0, o1;
    tf2x32(g2k0, g2k1, 0u, (uint32_t)i, o0, o1);   // counter hi=0, lo=i
    grand[i] = (int)((o0 ^ o1) & 4095u);           // bits = o0 ^ o1 (32-bit fold)
    tf2x32(r2k0, r2k1, 0u, (uint32_t)i, o0, o1);
    rrand[i] = (int)((o0 ^ o1) & 63u);
  }
#else
  // original mode: split(key) = threefry(key, iota(4)) pairs (0,2),(1,3)
  uint32_t a0, a1, b0, b1;
  tf2x32(0u, 42u, 0u, 2u, a0, a1);
  tf2x32(0u, 42u, 1u, 3u, b0, b1);
  uint32_t kg0 = a0, kg1 = b0, kr0 = a1, kr1 = b1;
  uint32_t c0, c1, d0, d1;
  tf2x32(kg0, kg1, 0u, 2u, c0, c1);
  tf2x32(kg0, kg1, 1u, 3u, d0, d1);
  uint32_t g2k0 = c1, g2k1 = d1;                 // k2 of kg
  tf2x32(kr0, kr1, 0u, 2u, c0, c1);
  tf2x32(kr0, kr1, 1u, 3u, d0, d1);
  uint32_t r2k0 = c1, r2k1 = d1;                 // k2 of kr
  if (i < 4096) {
    uint32_t o0, o1;
    tf2x32(g2k0, g2k1, (uint32_t)i, (uint32_t)(i + 4096), o0, o1);
    grand[i]        = (int)(o0 & 4095u);
    grand[i + 4096] = (int)(o1 & 4095u);
    tf2x32(r2k0, r2k1, (uint32_t)i, (uint32_t)(i + 4096), o0, o1);
    rrand[i]        = (int)(o0 & 63u);
    rrand[i + 4096] = (int)(o1 & 63u);
  }
#endif
}

// ---------------------------------------------------------------------------
__device__ __forceinline__ float softplus_f(float v) {
  return fmaxf(v, 0.0f) + log1pf(expf(-fabsf(v)));
}

// One block per (b,p): MLP -> means/sigmas -> indices, validity, weights.
// Also packs xsel rows for the Q projection GEMM.
__global__ __launch_bounds__(256) void params_kernel(
    const float* __restrict__ x,   // [B,T,EMB]
    const float* __restrict__ W1,  // [EMB+1,HID]
    const float* __restrict__ b1,  // [HID]
    const float* __restrict__ W2,  // [HID,2K]
    const float* __restrict__ b2,  // [2K]
    const int* __restrict__ grand, const int* __restrict__ rrand,
    float* __restrict__ xsel,      // [B*TP, EMB]
    int* __restrict__ idx_out,     // [B*TP, VS]
    float* __restrict__ w_out)     // [B*TP, VS]
{
  const int bp = blockIdx.x;           // 0..511
  const int b = bp >> 7, p = bp & 127;
  const int selp = STRIDE * p + STRIDE - 1;
  const int tid = threadIdx.x;

  __shared__ float sinp[EMB + 1];
  __shared__ float shid[HID];
  __shared__ float spartial[256];
  __shared__ float spar[2 * KMIX];
  __shared__ float sm[KMIX], ss[KMIX];
  __shared__ int   sidx[VS];
  __shared__ float sidxf[VS];
  __shared__ int   svalid[VS];
  __shared__ float sprops[KMIX][VS];
  __shared__ float sden[KMIX];

  // 1. load selected x row (+ write xsel for Q GEMM)
  float xv = x[((size_t)b * TT + selp) * EMB + tid];
  sinp[tid] = xv;
  xsel[(size_t)bp * EMB + tid] = xv;
  if (tid == 0) sinp[EMB] = (float)p / (float)TP;
  __syncthreads();

  // 2. hidden = relu(inp @ W1 + b1)
  for (int q = 0; q < HID / 256; q++) {
    int j = q * 256 + tid;
    float acc = 0.0f;
    for (int i = 0; i < EMB + 1; i++)
      acc = fmaf(sinp[i], W1[i * HID + j], acc);
    shid[j] = fmaxf(acc + b1[j], 0.0f);
  }
  __syncthreads();

  // 3. params = hidden @ W2 + b2  (16 outputs)
  {
    int o = tid & 15, g = tid >> 4;         // 16 groups of 64 j
    float pa = 0.0f;
    for (int jj = 0; jj < 64; jj++) {
      int j = g * 64 + jj;
      pa = fmaf(shid[j], W2[j * (2 * KMIX) + o], pa);
    }
    spartial[o * 16 + g] = pa;
  }
  __syncthreads();
  if (tid < 2 * KMIX) {
    float acc = 0.0f;
    for (int g = 0; g < 16; g++) acc += spartial[tid * 16 + g];
    spar[tid] = acc + b2[tid];
  }
  __syncthreads();

  // 4. means / sigmas
  if (tid < KMIX) {
    float m = (float)selp - 3.0f * softplus_f(spar[tid]);      // MMULT=3
    m = fminf(fmaxf(m, 0.0f), (float)(TT - 1));
    sm[tid] = m;
    float sg = ((softplus_f(spar[KMIX + tid] + 2.0f) + 0.05f) * (float)TT) * 0.1f;
    ss[tid] = sg;
  }
  __syncthreads();

  // 5. candidate indices: per k -> [fl, fl+1, g0, g1, r0, r1]
  if (tid < VS) {
    int kk = tid / 6, jj = tid % 6;
    float fl = floorf(sm[kk]);
    float v;
    if (jj == 0) v = fl;
    else if (jj == 1) v = fl + 1.0f;
    else if (jj < 4) v = (float)grand[(bp * KMIX + kk) * GADD + (jj - 2)];
    else {
      float lo = fminf(fmaxf(fl - (float)(REGION / 2), 0.0f), (float)(TT - REGION));
      v = lo + (float)rrand[(bp * KMIX + kk) * RADD + (jj - 4)];
    }
    v = fminf(fmaxf(v, 0.0f), (float)(TT - 1));
    int ii = (int)v;
    sidx[tid] = ii;
    sidxf[tid] = (float)ii;
  }
  __syncthreads();

  // 6. dup (lower-triangular) + causal validity
  if (tid < VS) {
    int d = 0;
    for (int u = 0; u < tid; u++) d |= (sidx[u] == sidx[tid]);
    svalid[tid] = (!d) && (sidx[tid] <= selp);
  }
  __syncthreads();

  // 7. props
  for (int l = tid; l < KMIX * VS; l += 256) {
    int kk = l / VS, v = l - kk * VS;
    float z = (sidxf[v] - sm[kk]) / ss[kk];
    sprops[kk][v] = svalid[v] ? expf(-0.5f * z * z) : 0.0f;
  }
  __syncthreads();
  if (tid < KMIX) {
    float den = 0.0f;
    for (int v = 0; v < VS; v++) den += sprops[tid][v];
    sden[tid] = den;
  }
  __syncthreads();

  // 8. weights = sum_k props/den
  if (tid < VS) {
    float w = 0.0f;
    for (int kk = 0; kk < KMIX; kk++) w += sprops[kk][tid] / sden[kk];
    w_out[(size_t)bp * VS + tid] = w;
    idx_out[(size_t)bp * VS + tid] = sidx[tid];
  }
}

// ---------------------------------------------------------------------------
// Generic fp32 GEMM: C[M,N] = scale * (A[M,256] @ W[256,N])
// BM=BN=128, BK=16, 256 threads, 8x8 per thread, float4 LDS.
// blockIdx.z picks (W0,C0) or (W1,C1) so K and V projections fuse in one launch.
// ---------------------------------------------------------------------------
__global__ __launch_bounds__(256) void gemm_k256(
    const float* __restrict__ A,
    const float* __restrict__ W0, const float* __restrict__ W1,
    float* __restrict__ C0, float* __restrict__ C1,
    int N, float scale)
{
  const float* W = (blockIdx.z == 0) ? W0 : W1;
  float* C = (blockIdx.z == 0) ? C0 : C1;

  const int tid = threadIdx.x;
  const int tx = tid & 15, ty = tid >> 4;
  const int m0 = blockIdx.y * 128, n0 = blockIdx.x * 128;

  __shared__ __align__(16) float AsT[16][128];
  __shared__ __align__(16) float Bs[16][128];

  float acc[8][8];
#pragma unroll
  for (int i = 0; i < 8; i++)
#pragma unroll
    for (int j = 0; j < 8; j++) acc[i][j] = 0.0f;

  for (int k0 = 0; k0 < EMB; k0 += 16) {
#pragma unroll
    for (int rep = 0; rep < 2; rep++) {
      int idx = rep * 1024 + tid * 4;
      int m = idx >> 4, kk = idx & 15;
      float4 v = *(const float4*)(A + (size_t)(m0 + m) * EMB + k0 + kk);
      AsT[kk + 0][m] = v.x; AsT[kk + 1][m] = v.y;
      AsT[kk + 2][m] = v.z; AsT[kk + 3][m] = v.w;
    }
#pragma unroll
    for (int rep = 0; rep < 2; rep++) {
      int idx = rep * 1024 + tid * 4;
      int kk = idx >> 7, n = idx & 127;
      *(float4*)(&Bs[kk][n]) = *(const float4*)(W + (size_t)(k0 + kk) * N + n0 + n);
    }
    __syncthreads();
#pragma unroll
    for (int kk = 0; kk < 16; kk++) {
      float a[8], bfr[8];
      *(float4*)&a[0] = *(const float4*)&AsT[kk][ty * 8];
      *(float4*)&a[4] = *(const float4*)&AsT[kk][ty * 8 + 4];
      *(float4*)&bfr[0] = *(const float4*)&Bs[kk][tx * 8];
      *(float4*)&bfr[4] = *(const float4*)&Bs[kk][tx * 8 + 4];
#pragma unroll
      for (int i = 0; i < 8; i++)
#pragma unroll
        for (int j = 0; j < 8; j++)
          acc[i][j] = fmaf(a[i], bfr[j], acc[i][j]);
    }
    __syncthreads();
  }
#pragma unroll
  for (int i = 0; i < 8; i++) {
    size_t row = (size_t)(m0 + ty * 8 + i);
    float* cp = C + row * N + n0 + tx * 8;
    float4 s0 = make_float4(acc[i][0] * scale, acc[i][1] * scale,
                            acc[i][2] * scale, acc[i][3] * scale);
    float4 s1 = make_float4(acc[i][4] * scale, acc[i][5] * scale,
                            acc[i][6] * scale, acc[i][7] * scale);
    *(float4*)cp = s0;
    *(float4*)(cp + 4) = s1;
  }
}

// ---------------------------------------------------------------------------
// Fill whole output with bu (non-sel rows of the reference are 0 @ Wu + bu).
// ---------------------------------------------------------------------------
__global__ void fill_out(const float* __restrict__ bu, float* __restrict__ out, int total) {
  int i = blockIdx.x * 256 + threadIdx.x;
  if (i < total) out[i] = bu[i & (EMB - 1)];
}

// ---------------------------------------------------------------------------
// Attention + Wu epilogue for one batch. One block per p.
// Qsel already scaled by 1/16 (= 1/e^0.5, both q and k scale folded).
// ---------------------------------------------------------------------------
__global__ __launch_bounds__(256) void attn_kernel(
    const float* __restrict__ Qsel,  // [B*TP, NQ]
    const float* __restrict__ Kb,    // [T, NQ]  (this batch)
    const float* __restrict__ Vb,    // [T, NQ]
    const int* __restrict__ idx_in,  // [B*TP, VS]
    const float* __restrict__ w_in,  // [B*TP, VS]
    const float* __restrict__ Wu,    // [NQ, EMB]
    const float* __restrict__ bu,    // [EMB]
    float* __restrict__ out,         // [B, T, EMB]
    int b)
{
  const int p = blockIdx.x;
  const int bp = b * TP + p;
  const int selp = STRIDE * p + STRIDE - 1;
  const int tid = threadIdx.x;

  __shared__ __align__(16) float q[NQ];
  __shared__ float sdot[HEADS][VS];
  __shared__ float satt[HEADS][VS];
  __shared__ float soutp[NQ];
  __shared__ int   sidx[VS];
  __shared__ float sw[VS];

#pragma unroll
  for (int r = 0; r < HEADS; r++)
    q[r * 256 + tid] = Qsel[(size_t)bp * NQ + r * 256 + tid];
  if (tid < VS) {
    sidx[tid] = idx_in[(size_t)bp * VS + tid];
    sw[tid] = w_in[(size_t)bp * VS + tid];
  }
  __syncthreads();

  // dots: 8 groups of 32 lanes; each group = one head, lane-split over EMB
  {
    const int h = tid >> 5, lane = tid & 31;
    for (int v = 0; v < VS; v++) {
      const float* kr = Kb + (size_t)sidx[v] * NQ + h * 256 + lane * 8;
      const float* qq = q + h * 256 + lane * 8;
      float4 k0 = *(const float4*)kr;
      float4 k1 = *(const float4*)(kr + 4);
      float par = qq[0] * k0.x + qq[1] * k0.y + qq[2] * k0.z + qq[3] * k0.w
                + qq[4] * k1.x + qq[5] * k1.y + qq[6] * k1.z + qq[7] * k1.w;
#pragma unroll
      for (int m = 16; m >= 1; m >>= 1) par += __shfl_xor(par, m, 64);
      if (lane == 0) sdot[h][v] = par;
    }
  }
  __syncthreads();

  // softmax over vs with score = weight * dot
  if (tid < HEADS) {
    float mx = -1e30f;
    for (int v = 0; v < VS; v++) mx = fmaxf(mx, sw[v] * sdot[tid][v]);
    float sum = 0.0f;
    for (int v = 0; v < VS; v++) {
      float e = expf(sw[v] * sdot[tid][v] - mx);
      satt[tid][v] = e;
      sum += e;
    }
    float inv = 1.0f / sum;
    for (int v = 0; v < VS; v++) satt[tid][v] *= inv;
  }
  __syncthreads();

  // outp[h][e]: thread tid = e, all 8 heads
  {
    float acc[HEADS];
#pragma unroll
    for (int h = 0; h < HEADS; h++) acc[h] = 0.0f;
    for (int v = 0; v < VS; v++) {
      const float* vr = Vb + (size_t)sidx[v] * NQ + tid;
#pragma unroll
      for (int h = 0; h < HEADS; h++)
        acc[h] = fmaf(satt[h][v], vr[h * 256], acc[h]);
    }
#pragma unroll
    for (int h = 0; h < HEADS; h++) soutp[h * 256 + tid] = acc[h];
  }
  __syncthreads();

  // out_row = outp @ Wu + bu
  {
    float o = bu[tid];
    for (int j = 0; j < NQ; j++)
      o = fmaf(soutp[j], Wu[j * EMB + tid], o);
    out[((size_t)b * TT + selp) * EMB + tid] = o;
  }
}

// ---------------------------------------------------------------------------
extern "C" void kernel_launch(void* const* d_in, const int* in_sizes, int n_in,
                              void* d_out, int out_size, void* d_ws, size_t ws_size,
                              hipStream_t stream) {
  const float* x  = (const float*)d_in[0];
  const float* Wq = (const float*)d_in[1];
  const float* Wk = (const float*)d_in[2];
  const float* Wv = (const float*)d_in[3];
  const float* Wu = (const float*)d_in[4];
  const float* bu = (const float*)d_in[5];
  const float* W1 = (const float*)d_in[6];
  const float* b1 = (const float*)d_in[7];
  const float* W2 = (const float*)d_in[8];
  const float* b2 = (const float*)d_in[9];
  float* out = (float*)d_out;

  // workspace layout (per-batch K/V reuse keeps footprint ~69 MB)
  char* ws = (char*)d_ws;
  const size_t KV = (size_t)TT * NQ * 4;           // 33554432
  float* Kb    = (float*)(ws);
  float* Vb    = (float*)(ws + KV);
  float* Qsel  = (float*)(ws + 2 * KV);                          // [512,2048]
  float* xsel  = (float*)(ws + 2 * KV + 4194304);                // [512,256]
  int*   idxb  = (int*)  (ws + 2 * KV + 4194304 + 524288);       // [512,48]
  float* wts   = (float*)(ws + 2 * KV + 4194304 + 524288 + 98304);
  int*   grand = (int*)  (ws + 2 * KV + 4194304 + 524288 + 2 * 98304);
  int*   rrand = (int*)  (ws + 2 * KV + 4194304 + 524288 + 2 * 98304 + 32768);

  // 1. RNG (exact JAX threefry reproduction)
  rand_kernel<<<dim3(32), dim3(256), 0, stream>>>(grand, rrand);

  // 2. MLP / indices / weights (+ packs xsel)
  params_kernel<<<dim3(BB * TP), dim3(256), 0, stream>>>(
      x, W1, b1, W2, b2, grand, rrand, xsel, idxb, wts);

  // 3. Q projection at sel rows, scale 1/16 folds both q and k 1/e^0.25 factors
  gemm_k256<<<dim3(NQ / 128, (BB * TP) / 128, 1), dim3(256), 0, stream>>>(
      xsel, Wq, Wq, Qsel, Qsel, NQ, 0.0625f);

  // 4. background output rows = bu
  fill_out<<<dim3((BB * TT * EMB) / 256), dim3(256), 0, stream>>>(
      bu, out, BB * TT * EMB);

  // 5. per-batch: K,V projection (fused via grid.z) then attention+epilogue
  for (int b = 0; b < BB; b++) {
    const float* xb = x + (size_t)b * TT * EMB;
    gemm_k256<<<dim3(NQ / 128, TT / 128, 2), dim3(256), 0, stream>>>(
        xb, Wk, Wv, Kb, Vb, NQ, 1.0f);
    attn_kernel<<<dim3(TP), dim3(256), 0, stream>>>(
        Qsel, Kb, Vb, idxb, wts, Wu, bu, out, b);
  }
}

// Round 2
// 675.789 us; speedup vs baseline: 1.3111x; 1.3111x over previous
//
#include <hip/hip_runtime.h>
#include <stdint.h>

// ---------------------------------------------------------------------------
// Problem constants (from reference)
// ---------------------------------------------------------------------------
#define EMB   256
#define HEADS 8
#define KMIX  8
#define GADD  2
#define RADD  2
#define REGION 64
#define STRIDE 32
#define BB    4
#define TT    4096
#define TP    128
#define VS    48
#define HID   1024
#define NQ    2048

#define RNG_PARTITIONABLE 1

typedef short short8v __attribute__((ext_vector_type(8)));
typedef float float4v __attribute__((ext_vector_type(4)));

#define LDS_PTR(x) ((__attribute__((address_space(3))) void*)(x))
#define GLB_PTR(x) ((const __attribute__((address_space(1))) void*)(x))

// ---------------------------------------------------------------------------
// bf16 helpers (RNE)
// ---------------------------------------------------------------------------
__device__ __forceinline__ short f2bf(float f) {
  uint32_t u = __float_as_uint(f);
  u += 0x7FFFu + ((u >> 16) & 1u);
  return (short)(u >> 16);
}
__device__ __forceinline__ float bf2f(short h) {
  return __uint_as_float(((uint32_t)(uint16_t)h) << 16);
}

// ---------------------------------------------------------------------------
// Threefry-2x32 (JAX exact)
// ---------------------------------------------------------------------------
__device__ __forceinline__ uint32_t rotl32(uint32_t x, int d) {
  return (x << d) | (x >> (32 - d));
}
__device__ __forceinline__ void tf2x32(uint32_t k0, uint32_t k1,
                                       uint32_t x0, uint32_t x1,
                                       uint32_t& o0, uint32_t& o1) {
  uint32_t ks2 = k0 ^ k1 ^ 0x1BD11BDAu;
  x0 += k0; x1 += k1;
#define TFR(r) { x0 += x1; x1 = rotl32(x1, r); x1 ^= x0; }
  TFR(13) TFR(15) TFR(26) TFR(6)
  x0 += k1; x1 += ks2 + 1u;
  TFR(17) TFR(29) TFR(16) TFR(24)
  x0 += ks2; x1 += k0 + 2u;
  TFR(13) TFR(15) TFR(26) TFR(6)
  x0 += k0; x1 += k1 + 3u;
  TFR(17) TFR(29) TFR(16) TFR(24)
  x0 += k1; x1 += ks2 + 4u;
  TFR(13) TFR(15) TFR(26) TFR(6)
  x0 += ks2; x1 += k0 + 5u;
#undef TFR
  o0 = x0; o1 = x1;
}

__global__ void rand_kernel(int* __restrict__ grand, int* __restrict__ rrand) {
  int i = blockIdx.x * blockDim.x + threadIdx.x;
#if RNG_PARTITIONABLE
  uint32_t kg0, kg1, kr0, kr1;
  tf2x32(0u, 42u, 0u, 0u, kg0, kg1);
  tf2x32(0u, 42u, 0u, 1u, kr0, kr1);
  uint32_t g2k0, g2k1, r2k0, r2k1;
  tf2x32(kg0, kg1, 0u, 1u, g2k0, g2k1);
  tf2x32(kr0, kr1, 0u, 1u, r2k0, r2k1);
  if (i < BB * TP * KMIX * GADD) {
    uint32_t o0, o1;
    tf2x32(g2k0, g2k1, 0u, (uint32_t)i, o0, o1);
    grand[i] = (int)((o0 ^ o1) & 4095u);
    tf2x32(r2k0, r2k1, 0u, (uint32_t)i, o0, o1);
    rrand[i] = (int)((o0 ^ o1) & 63u);
  }
#else
  uint32_t a0, a1, b0, b1;
  tf2x32(0u, 42u, 0u, 2u, a0, a1);
  tf2x32(0u, 42u, 1u, 3u, b0, b1);
  uint32_t kg0 = a0, kg1 = b0, kr0 = a1, kr1 = b1;
  uint32_t c0, c1, d0, d1;
  tf2x32(kg0, kg1, 0u, 2u, c0, c1);
  tf2x32(kg0, kg1, 1u, 3u, d0, d1);
  uint32_t g2k0 = c1, g2k1 = d1;
  tf2x32(kr0, kr1, 0u, 2u, c0, c1);
  tf2x32(kr0, kr1, 1u, 3u, d0, d1);
  uint32_t r2k0 = c1, r2k1 = d1;
  if (i < 4096) {
    uint32_t o0, o1;
    tf2x32(g2k0, g2k1, (uint32_t)i, (uint32_t)(i + 4096), o0, o1);
    grand[i]        = (int)(o0 & 4095u);
    grand[i + 4096] = (int)(o1 & 4095u);
    tf2x32(r2k0, r2k1, (uint32_t)i, (uint32_t)(i + 4096), o0, o1);
    rrand[i]        = (int)(o0 & 63u);
    rrand[i + 4096] = (int)(o1 & 63u);
  }
#endif
}

// ---------------------------------------------------------------------------
// Prepass: split x into bf16 hi/lo  [B*T, EMB]
// ---------------------------------------------------------------------------
__global__ __launch_bounds__(256) void prep_x_split(
    const float* __restrict__ x, short* __restrict__ Xh, short* __restrict__ Xl) {
  size_t i8 = ((size_t)blockIdx.x * 256 + threadIdx.x) * 8;
  float4 v0 = *(const float4*)(x + i8);
  float4 v1 = *(const float4*)(x + i8 + 4);
  float f[8] = {v0.x, v0.y, v0.z, v0.w, v1.x, v1.y, v1.z, v1.w};
  short8v hh, ll;
#pragma unroll
  for (int j = 0; j < 8; j++) {
    short h = f2bf(f[j]);
    hh[j] = h;
    ll[j] = f2bf(f[j] - bf2f(h));
  }
  *(short8v*)(Xh + i8) = hh;
  *(short8v*)(Xl + i8) = ll;
}

// ---------------------------------------------------------------------------
// Prepass: transpose+split Wq/Wk/Wv [256,2048] -> Wt hi/lo [2048,256]
// ---------------------------------------------------------------------------
__global__ __launch_bounds__(256) void prep_w_split(
    const float* __restrict__ Wq, const float* __restrict__ Wk, const float* __restrict__ Wv,
    short* __restrict__ Qh, short* __restrict__ Ql,
    short* __restrict__ Kh, short* __restrict__ Kl,
    short* __restrict__ Vh, short* __restrict__ Vl) {
  const float* W; short *Oh, *Ol;
  if (blockIdx.z == 0)      { W = Wq; Oh = Qh; Ol = Ql; }
  else if (blockIdx.z == 1) { W = Wk; Oh = Kh; Ol = Kl; }
  else                      { W = Wv; Oh = Vh; Ol = Vl; }
  __shared__ float tile[32][33];
  const int tx = threadIdx.x & 31, trow = threadIdx.x >> 5;
  const int n0 = blockIdx.x * 32, k0 = blockIdx.y * 32;
#pragma unroll
  for (int i = 0; i < 4; i++) {
    int k = trow + i * 8;
    tile[k][tx] = W[(size_t)(k0 + k) * NQ + n0 + tx];
  }
  __syncthreads();
#pragma unroll
  for (int i = 0; i < 4; i++) {
    int n = trow + i * 8;
    float f = tile[tx][n];
    short h = f2bf(f);
    Oh[(size_t)(n0 + n) * EMB + k0 + tx] = h;
    Ol[(size_t)(n0 + n) * EMB + k0 + tx] = f2bf(f - bf2f(h));
  }
}

// ---------------------------------------------------------------------------
// Prepass: extract sel rows of x -> xsel (f32) + bf16 hi/lo splits
// ---------------------------------------------------------------------------
__global__ __launch_bounds__(256) void prep_sel(
    const float* __restrict__ x, float* __restrict__ xsel,
    short* __restrict__ xh, short* __restrict__ xl) {
  const int bp = blockIdx.x, b = bp >> 7, p = bp & 127;
  const int selp = STRIDE * p + STRIDE - 1;
  const int tid = threadIdx.x;
  float f = x[((size_t)b * TT + selp) * EMB + tid];
  xsel[(size_t)bp * EMB + tid] = f;
  short h = f2bf(f);
  xh[(size_t)bp * EMB + tid] = h;
  xl[(size_t)bp * EMB + tid] = f2bf(f - bf2f(h));
}

// ---------------------------------------------------------------------------
// Split-bf16 MFMA GEMM: C[M,2048] = scale * (A[M,256] @ W[256,2048])
// A given as hi/lo bf16 [M,256]; W given TRANSPOSED hi/lo bf16 [2048,256].
// 128x128 tile, BK=32, 4 waves (2x2, 64x64 each), mfma_f32_16x16x32_bf16 x3.
// LDS layout per matrix/split: [kg=4][row=128][8 bf16] -> frag reads are
// lane-consecutive ds_read_b128 (conflict-free). Staged via global_load_lds
// width=16 with per-lane global source addresses.
// ---------------------------------------------------------------------------
__global__ __launch_bounds__(256) void gemm_split(
    const short* __restrict__ Ah_g, const short* __restrict__ Al_g,
    const short* __restrict__ B0h, const short* __restrict__ B0l,
    const short* __restrict__ B1h, const short* __restrict__ B1l,
    float* __restrict__ C0, float* __restrict__ C1, float scale)
{
  const short* Bh_g = (blockIdx.z == 0) ? B0h : B1h;
  const short* Bl_g = (blockIdx.z == 0) ? B0l : B1l;
  float* C = (blockIdx.z == 0) ? C0 : C1;

  const int tid = threadIdx.x;
  const int wid = tid >> 6, lane = tid & 63;
  const int wr = wid >> 1, wc = wid & 1;
  const int m0 = blockIdx.y * 128, n0 = blockIdx.x * 128;

  __shared__ __align__(16) short Ah[4096], Al[4096], Bh[4096], Bl[4096];

  // wave -> staging target
  const char* gbase;
  short* lbase;
  if (wid == 0)      { gbase = (const char*)(Ah_g) + (size_t)(m0 + lane) * 512; lbase = Ah; }
  else if (wid == 1) { gbase = (const char*)(Al_g) + (size_t)(m0 + lane) * 512; lbase = Al; }
  else if (wid == 2) { gbase = (const char*)(Bh_g) + (size_t)(n0 + lane) * 512; lbase = Bh; }
  else               { gbase = (const char*)(Bl_g) + (size_t)(n0 + lane) * 512; lbase = Bl; }

  float4v acc[4][4];
#pragma unroll
  for (int i = 0; i < 4; i++)
#pragma unroll
    for (int j = 0; j < 4; j++) acc[i][j] = (float4v)0.0f;

  const int aoff = (lane >> 4) * 1024 + (wr * 64 + (lane & 15)) * 8;
  const int boff = (lane >> 4) * 1024 + (wc * 64 + (lane & 15)) * 8;

  for (int ks = 0; ks < 8; ks++) {
    const int k0b = ks * 64;   // byte offset of k0 within a 512B row (k0*2)
    // stage this K-slice: 8 chunks of 64 lanes x 16B per wave
#pragma unroll
    for (int c = 0; c < 8; c++) {
      const char* src = gbase + k0b + (c & 1) * (64 * 512) + (c >> 1) * 16;
      __builtin_amdgcn_global_load_lds(GLB_PTR(src), LDS_PTR(lbase + c * 512), 16, 0, 0);
    }
    __syncthreads();

    short8v ah[4], al[4], bh[4], bl[4];
#pragma unroll
    for (int mf = 0; mf < 4; mf++) {
      ah[mf] = *(const short8v*)(Ah + aoff + mf * 128);
      al[mf] = *(const short8v*)(Al + aoff + mf * 128);
    }
#pragma unroll
    for (int nf = 0; nf < 4; nf++) {
      bh[nf] = *(const short8v*)(Bh + boff + nf * 128);
      bl[nf] = *(const short8v*)(Bl + boff + nf * 128);
    }
#pragma unroll
    for (int mf = 0; mf < 4; mf++)
#pragma unroll
      for (int nf = 0; nf < 4; nf++) {
        acc[mf][nf] = __builtin_amdgcn_mfma_f32_16x16x32_bf16(ah[mf], bh[nf], acc[mf][nf], 0, 0, 0);
        acc[mf][nf] = __builtin_amdgcn_mfma_f32_16x16x32_bf16(ah[mf], bl[nf], acc[mf][nf], 0, 0, 0);
        acc[mf][nf] = __builtin_amdgcn_mfma_f32_16x16x32_bf16(al[mf], bh[nf], acc[mf][nf], 0, 0, 0);
      }
    __syncthreads();
  }

  // epilogue: C/D layout col=lane&15, row=(lane>>4)*4+r
#pragma unroll
  for (int mf = 0; mf < 4; mf++) {
#pragma unroll
    for (int nf = 0; nf < 4; nf++) {
      int crow = m0 + wr * 64 + mf * 16 + (lane >> 4) * 4;
      int ccol = n0 + wc * 64 + nf * 16 + (lane & 15);
      float* cp = C + (size_t)crow * NQ + ccol;
#pragma unroll
      for (int r = 0; r < 4; r++)
        cp[(size_t)r * NQ] = acc[mf][nf][r] * scale;
    }
  }
}

// ---------------------------------------------------------------------------
// fp32 GEMM (kept for the small MLP): C[M,N] = scale*(A[M,256] @ W[256,N])
// ---------------------------------------------------------------------------
__global__ __launch_bounds__(256) void gemm_k256(
    const float* __restrict__ A,
    const float* __restrict__ W0, const float* __restrict__ W1,
    float* __restrict__ C0, float* __restrict__ C1,
    int N, float scale)
{
  const float* W = (blockIdx.z == 0) ? W0 : W1;
  float* C = (blockIdx.z == 0) ? C0 : C1;

  const int tid = threadIdx.x;
  const int tx = tid & 15, ty = tid >> 4;
  const int m0 = blockIdx.y * 128, n0 = blockIdx.x * 128;

  __shared__ __align__(16) float AsT[16][128];
  __shared__ __align__(16) float Bs[16][128];

  float acc[8][8];
#pragma unroll
  for (int i = 0; i < 8; i++)
#pragma unroll
    for (int j = 0; j < 8; j++) acc[i][j] = 0.0f;

  for (int k0 = 0; k0 < EMB; k0 += 16) {
#pragma unroll
    for (int rep = 0; rep < 2; rep++) {
      int idx = rep * 1024 + tid * 4;
      int m = idx >> 4, kk = idx & 15;
      float4 v = *(const float4*)(A + (size_t)(m0 + m) * EMB + k0 + kk);
      AsT[kk + 0][m] = v.x; AsT[kk + 1][m] = v.y;
      AsT[kk + 2][m] = v.z; AsT[kk + 3][m] = v.w;
    }
#pragma unroll
    for (int rep = 0; rep < 2; rep++) {
      int idx = rep * 1024 + tid * 4;
      int kk = idx >> 7, n = idx & 127;
      *(float4*)(&Bs[kk][n]) = *(const float4*)(W + (size_t)(k0 + kk) * N + n0 + n);
    }
    __syncthreads();
#pragma unroll
    for (int kk = 0; kk < 16; kk++) {
      float a[8], bfr[8];
      *(float4*)&a[0] = *(const float4*)&AsT[kk][ty * 8];
      *(float4*)&a[4] = *(const float4*)&AsT[kk][ty * 8 + 4];
      *(float4*)&bfr[0] = *(const float4*)&Bs[kk][tx * 8];
      *(float4*)&bfr[4] = *(const float4*)&Bs[kk][tx * 8 + 4];
#pragma unroll
      for (int i = 0; i < 8; i++)
#pragma unroll
        for (int j = 0; j < 8; j++)
          acc[i][j] = fmaf(a[i], bfr[j], acc[i][j]);
    }
    __syncthreads();
  }
#pragma unroll
  for (int i = 0; i < 8; i++) {
    size_t row = (size_t)(m0 + ty * 8 + i);
    float* cp = C + row * N + n0 + tx * 8;
    float4 s0 = make_float4(acc[i][0] * scale, acc[i][1] * scale,
                            acc[i][2] * scale, acc[i][3] * scale);
    float4 s1 = make_float4(acc[i][4] * scale, acc[i][5] * scale,
                            acc[i][6] * scale, acc[i][7] * scale);
    *(float4*)cp = s0;
    *(float4*)(cp + 4) = s1;
  }
}

// ---------------------------------------------------------------------------
__device__ __forceinline__ float softplus_f(float v) {
  return fmaxf(v, 0.0f) + log1pf(expf(-fabsf(v)));
}

// Per (b,p): finish MLP (coord col + bias + relu), head, indices, weights.
__global__ __launch_bounds__(256) void params2_kernel(
    const float* __restrict__ hid0,  // [512, HID] = xsel @ W1[0:256]
    const float* __restrict__ W1,    // [257, HID] (row 256 = coord row)
    const float* __restrict__ b1,
    const float* __restrict__ W2,    // [HID, 16]
    const float* __restrict__ b2,
    const int* __restrict__ grand, const int* __restrict__ rrand,
    int* __restrict__ idx_out, float* __restrict__ w_out)
{
  const int bp = blockIdx.x;
  const int b = bp >> 7, p = bp & 127;
  const int selp = STRIDE * p + STRIDE - 1;
  const int tid = threadIdx.x;
  const float coordp = (float)p / (float)TP;

  __shared__ float shid[HID];
  __shared__ float spartial[256];
  __shared__ float spar[2 * KMIX];
  __shared__ float sm[KMIX], ss[KMIX];
  __shared__ int   sidx[VS];
  __shared__ float sidxf[VS];
  __shared__ int   svalid[VS];
  __shared__ float sprops[KMIX][VS];
  __shared__ float sden[KMIX];

#pragma unroll
  for (int q = 0; q < HID / 256; q++) {
    int j = q * 256 + tid;
    shid[j] = fmaxf(hid0[(size_t)bp * HID + j] + coordp * W1[(size_t)EMB * HID + j] + b1[j], 0.0f);
  }
  __syncthreads();

  {
    int o = tid & 15, g = tid >> 4;
    float pa = 0.0f;
    for (int jj = 0; jj < 64; jj++) {
      int j = g * 64 + jj;
      pa = fmaf(shid[j], W2[j * (2 * KMIX) + o], pa);
    }
    spartial[o * 16 + g] = pa;
  }
  __syncthreads();
  if (tid < 2 * KMIX) {
    float acc = 0.0f;
    for (int g = 0; g < 16; g++) acc += spartial[tid * 16 + g];
    spar[tid] = acc + b2[tid];
  }
  __syncthreads();

  if (tid < KMIX) {
    float m = (float)selp - 3.0f * softplus_f(spar[tid]);
    m = fminf(fmaxf(m, 0.0f), (float)(TT - 1));
    sm[tid] = m;
    ss[tid] = (softplus_f(spar[KMIX + tid] + 2.0f) + 0.05f) * (float)TT * 0.1f;
  }
  __syncthreads();

  if (tid < VS) {
    int kk = tid / 6, jj = tid % 6;
    float fl = floorf(sm[kk]);
    float v;
    if (jj == 0) v = fl;
    else if (jj == 1) v = fl + 1.0f;
    else if (jj < 4) v = (float)grand[(bp * KMIX + kk) * GADD + (jj - 2)];
    else {
      float lo = fminf(fmaxf(fl - (float)(REGION / 2), 0.0f), (float)(TT - REGION));
      v = lo + (float)rrand[(bp * KMIX + kk) * RADD + (jj - 4)];
    }
    v = fminf(fmaxf(v, 0.0f), (float)(TT - 1));
    int ii = (int)v;
    sidx[tid] = ii;
    sidxf[tid] = (float)ii;
  }
  __syncthreads();

  if (tid < VS) {
    int d = 0;
    for (int u = 0; u < tid; u++) d |= (sidx[u] == sidx[tid]);
    svalid[tid] = (!d) && (sidx[tid] <= selp);
  }
  __syncthreads();

  for (int l = tid; l < KMIX * VS; l += 256) {
    int kk = l / VS, v = l - kk * VS;
    float z = (sidxf[v] - sm[kk]) / ss[kk];
    sprops[kk][v] = svalid[v] ? expf(-0.5f * z * z) : 0.0f;
  }
  __syncthreads();
  if (tid < KMIX) {
    float den = 0.0f;
    for (int v = 0; v < VS; v++) den += sprops[tid][v];
    sden[tid] = den;
  }
  __syncthreads();

  if (tid < VS) {
    float w = 0.0f;
    for (int kk = 0; kk < KMIX; kk++) w += sprops[kk][tid] / sden[kk];
    w_out[(size_t)bp * VS + tid] = w;
    idx_out[(size_t)bp * VS + tid] = sidx[tid];
  }
}

// ---------------------------------------------------------------------------
__global__ void fill_out(const float* __restrict__ bu, float* __restrict__ out, int total) {
  int i = blockIdx.x * 256 + threadIdx.x;
  if (i < total) out[i] = bu[i & (EMB - 1)];
}

// ---------------------------------------------------------------------------
// Attention + Wu epilogue for one batch. One block per p.
// ---------------------------------------------------------------------------
__global__ __launch_bounds__(256) void attn_kernel(
    const float* __restrict__ Qsel,
    const float* __restrict__ Kb,
    const float* __restrict__ Vb,
    const int* __restrict__ idx_in,
    const float* __restrict__ w_in,
    const float* __restrict__ Wu,
    const float* __restrict__ bu,
    float* __restrict__ out,
    int b)
{
  const int p = blockIdx.x;
  const int bp = b * TP + p;
  const int selp = STRIDE * p + STRIDE - 1;
  const int tid = threadIdx.x;

  __shared__ __align__(16) float q[NQ];
  __shared__ float sdot[HEADS][VS];
  __shared__ float satt[HEADS][VS];
  __shared__ float soutp[NQ];
  __shared__ int   sidx[VS];
  __shared__ float sw[VS];

#pragma unroll
  for (int r = 0; r < HEADS; r++)
    q[r * 256 + tid] = Qsel[(size_t)bp * NQ + r * 256 + tid];
  if (tid < VS) {
    sidx[tid] = idx_in[(size_t)bp * VS + tid];
    sw[tid] = w_in[(size_t)bp * VS + tid];
  }
  __syncthreads();

  {
    const int h = tid >> 5, lane = tid & 31;
    for (int v = 0; v < VS; v++) {
      const float* kr = Kb + (size_t)sidx[v] * NQ + h * 256 + lane * 8;
      const float* qq = q + h * 256 + lane * 8;
      float4 k0 = *(const float4*)kr;
      float4 k1 = *(const float4*)(kr + 4);
      float par = qq[0] * k0.x + qq[1] * k0.y + qq[2] * k0.z + qq[3] * k0.w
                + qq[4] * k1.x + qq[5] * k1.y + qq[6] * k1.z + qq[7] * k1.w;
#pragma unroll
      for (int m = 16; m >= 1; m >>= 1) par += __shfl_xor(par, m, 64);
      if (lane == 0) sdot[h][v] = par;
    }
  }
  __syncthreads();

  if (tid < HEADS) {
    float mx = -1e30f;
    for (int v = 0; v < VS; v++) mx = fmaxf(mx, sw[v] * sdot[tid][v]);
    float sum = 0.0f;
    for (int v = 0; v < VS; v++) {
      float e = expf(sw[v] * sdot[tid][v] - mx);
      satt[tid][v] = e;
      sum += e;
    }
    float inv = 1.0f / sum;
    for (int v = 0; v < VS; v++) satt[tid][v] *= inv;
  }
  __syncthreads();

  {
    float acc[HEADS];
#pragma unroll
    for (int h = 0; h < HEADS; h++) acc[h] = 0.0f;
    for (int v = 0; v < VS; v++) {
      const float* vr = Vb + (size_t)sidx[v] * NQ + tid;
#pragma unroll
      for (int h = 0; h < HEADS; h++)
        acc[h] = fmaf(satt[h][v], vr[h * 256], acc[h]);
    }
#pragma unroll
    for (int h = 0; h < HEADS; h++) soutp[h * 256 + tid] = acc[h];
  }
  __syncthreads();

  {
    float o = bu[tid];
    for (int j = 0; j < NQ; j++)
      o = fmaf(soutp[j], Wu[j * EMB + tid], o);
    out[((size_t)b * TT + selp) * EMB + tid] = o;
  }
}

// ---------------------------------------------------------------------------
extern "C" void kernel_launch(void* const* d_in, const int* in_sizes, int n_in,
                              void* d_out, int out_size, void* d_ws, size_t ws_size,
                              hipStream_t stream) {
  const float* x  = (const float*)d_in[0];
  const float* Wq = (const float*)d_in[1];
  const float* Wk = (const float*)d_in[2];
  const float* Wv = (const float*)d_in[3];
  const float* Wu = (const float*)d_in[4];
  const float* bu = (const float*)d_in[5];
  const float* W1 = (const float*)d_in[6];
  const float* b1 = (const float*)d_in[7];
  const float* W2 = (const float*)d_in[8];
  const float* b2 = (const float*)d_in[9];
  float* out = (float*)d_out;

  // ---- workspace layout ----
  char* ws = (char*)d_ws;
  size_t off = 0;
  auto alloc = [&](size_t bytes) { char* p = ws + off; off += (bytes + 255) & ~(size_t)255; return p; };
  float* Kb    = (float*)alloc((size_t)TT * NQ * 4);        // 32 MB
  float* Vb    = (float*)alloc((size_t)TT * NQ * 4);        // 32 MB
  float* Qsel  = (float*)alloc((size_t)BB * TP * NQ * 4);   // 4 MB
  short* Xh    = (short*)alloc((size_t)BB * TT * EMB * 2);  // 8 MB
  short* Xl    = (short*)alloc((size_t)BB * TT * EMB * 2);  // 8 MB
  short* Wqth  = (short*)alloc((size_t)NQ * EMB * 2);
  short* Wqtl  = (short*)alloc((size_t)NQ * EMB * 2);
  short* Wkth  = (short*)alloc((size_t)NQ * EMB * 2);
  short* Wktl  = (short*)alloc((size_t)NQ * EMB * 2);
  short* Wvth  = (short*)alloc((size_t)NQ * EMB * 2);
  short* Wvtl  = (short*)alloc((size_t)NQ * EMB * 2);
  float* xsel  = (float*)alloc((size_t)BB * TP * EMB * 4);
  short* xselh = (short*)alloc((size_t)BB * TP * EMB * 2);
  short* xsell = (short*)alloc((size_t)BB * TP * EMB * 2);
  float* hid0  = (float*)alloc((size_t)BB * TP * HID * 4);  // 2 MB
  int*   idxb  = (int*)  alloc((size_t)BB * TP * VS * 4);
  float* wts   = (float*)alloc((size_t)BB * TP * VS * 4);
  int*   grand = (int*)  alloc((size_t)BB * TP * KMIX * GADD * 4);
  int*   rrand = (int*)  alloc((size_t)BB * TP * KMIX * RADD * 4);

  // 1. RNG + prepasses
  rand_kernel<<<dim3(32), dim3(256), 0, stream>>>(grand, rrand);
  prep_x_split<<<dim3((BB * TT * EMB) / (256 * 8)), dim3(256), 0, stream>>>(x, Xh, Xl);
  prep_w_split<<<dim3(NQ / 32, EMB / 32, 3), dim3(256), 0, stream>>>(
      Wq, Wk, Wv, Wqth, Wqtl, Wkth, Wktl, Wvth, Wvtl);
  prep_sel<<<dim3(BB * TP), dim3(256), 0, stream>>>(x, xsel, xselh, xsell);

  // 2. MLP gemm (fp32) + params finish
  gemm_k256<<<dim3(HID / 128, (BB * TP) / 128, 1), dim3(256), 0, stream>>>(
      xsel, W1, W1, hid0, hid0, HID, 1.0f);
  params2_kernel<<<dim3(BB * TP), dim3(256), 0, stream>>>(
      hid0, W1, b1, W2, b2, grand, rrand, idxb, wts);

  // 3. Q projection (split-bf16 MFMA), scale 1/16 folds both 1/e^0.25 factors
  gemm_split<<<dim3(NQ / 128, (BB * TP) / 128, 1), dim3(256), 0, stream>>>(
      xselh, xsell, Wqth, Wqtl, Wqth, Wqtl, Qsel, Qsel, 0.0625f);

  // 4. background output rows = bu
  fill_out<<<dim3((BB * TT * EMB) / 256), dim3(256), 0, stream>>>(
      bu, out, BB * TT * EMB);

  // 5. per-batch K/V projection (MFMA) + attention
  for (int b = 0; b < BB; b++) {
    const short* xbh = Xh + (size_t)b * TT * EMB;
    const short* xbl = Xl + (size_t)b * TT * EMB;
    gemm_split<<<dim3(NQ / 128, TT / 128, 2), dim3(256), 0, stream>>>(
        xbh, xbl, Wkth, Wktl, Wvth, Wvtl, Kb, Vb, 1.0f);
    attn_kernel<<<dim3(TP), dim3(256), 0, stream>>>(
        Qsel, Kb, Vb, idxb, wts, Wu, bu, out, b);
  }
}

// Round 3
// 512.388 us; speedup vs baseline: 1.7292x; 1.3189x over previous
//
#include <hip/hip_runtime.h>
#include <stdint.h>

// ---------------------------------------------------------------------------
// Problem constants (from reference)
// ---------------------------------------------------------------------------
#define EMB   256
#define HEADS 8
#define KMIX  8
#define GADD  2
#define RADD  2
#define REGION 64
#define STRIDE 32
#define BB    4
#define TT    4096
#define TP    128
#define VS    48
#define HID   1024
#define NQ    2048

#define RNG_PARTITIONABLE 1

typedef short short8v __attribute__((ext_vector_type(8)));
typedef float float4v __attribute__((ext_vector_type(4)));

#define LDS_PTR(x) ((__attribute__((address_space(3))) void*)(x))
#define GLB_PTR(x) ((const __attribute__((address_space(1))) void*)(x))

// ---------------------------------------------------------------------------
// bf16 helpers (RNE)
// ---------------------------------------------------------------------------
__device__ __forceinline__ short f2bf(float f) {
  uint32_t u = __float_as_uint(f);
  u += 0x7FFFu + ((u >> 16) & 1u);
  return (short)(u >> 16);
}
__device__ __forceinline__ float bf2f(short h) {
  return __uint_as_float(((uint32_t)(uint16_t)h) << 16);
}

// ---------------------------------------------------------------------------
// Threefry-2x32 (JAX exact)
// ---------------------------------------------------------------------------
__device__ __forceinline__ uint32_t rotl32(uint32_t x, int d) {
  return (x << d) | (x >> (32 - d));
}
__device__ __forceinline__ void tf2x32(uint32_t k0, uint32_t k1,
                                       uint32_t x0, uint32_t x1,
                                       uint32_t& o0, uint32_t& o1) {
  uint32_t ks2 = k0 ^ k1 ^ 0x1BD11BDAu;
  x0 += k0; x1 += k1;
#define TFR(r) { x0 += x1; x1 = rotl32(x1, r); x1 ^= x0; }
  TFR(13) TFR(15) TFR(26) TFR(6)
  x0 += k1; x1 += ks2 + 1u;
  TFR(17) TFR(29) TFR(16) TFR(24)
  x0 += ks2; x1 += k0 + 2u;
  TFR(13) TFR(15) TFR(26) TFR(6)
  x0 += k0; x1 += k1 + 3u;
  TFR(17) TFR(29) TFR(16) TFR(24)
  x0 += k1; x1 += ks2 + 4u;
  TFR(13) TFR(15) TFR(26) TFR(6)
  x0 += ks2; x1 += k0 + 5u;
#undef TFR
  o0 = x0; o1 = x1;
}

__global__ void rand_kernel(int* __restrict__ grand, int* __restrict__ rrand) {
  int i = blockIdx.x * blockDim.x + threadIdx.x;
#if RNG_PARTITIONABLE
  uint32_t kg0, kg1, kr0, kr1;
  tf2x32(0u, 42u, 0u, 0u, kg0, kg1);
  tf2x32(0u, 42u, 0u, 1u, kr0, kr1);
  uint32_t g2k0, g2k1, r2k0, r2k1;
  tf2x32(kg0, kg1, 0u, 1u, g2k0, g2k1);
  tf2x32(kr0, kr1, 0u, 1u, r2k0, r2k1);
  if (i < BB * TP * KMIX * GADD) {
    uint32_t o0, o1;
    tf2x32(g2k0, g2k1, 0u, (uint32_t)i, o0, o1);
    grand[i] = (int)((o0 ^ o1) & 4095u);
    tf2x32(r2k0, r2k1, 0u, (uint32_t)i, o0, o1);
    rrand[i] = (int)((o0 ^ o1) & 63u);
  }
#else
  uint32_t a0, a1, b0, b1;
  tf2x32(0u, 42u, 0u, 2u, a0, a1);
  tf2x32(0u, 42u, 1u, 3u, b0, b1);
  uint32_t kg0 = a0, kg1 = b0, kr0 = a1, kr1 = b1;
  uint32_t c0, c1, d0, d1;
  tf2x32(kg0, kg1, 0u, 2u, c0, c1);
  tf2x32(kg0, kg1, 1u, 3u, d0, d1);
  uint32_t g2k0 = c1, g2k1 = d1;
  tf2x32(kr0, kr1, 0u, 2u, c0, c1);
  tf2x32(kr0, kr1, 1u, 3u, d0, d1);
  uint32_t r2k0 = c1, r2k1 = d1;
  if (i < 4096) {
    uint32_t o0, o1;
    tf2x32(g2k0, g2k1, (uint32_t)i, (uint32_t)(i + 4096), o0, o1);
    grand[i]        = (int)(o0 & 4095u);
    grand[i + 4096] = (int)(o1 & 4095u);
    tf2x32(r2k0, r2k1, (uint32_t)i, (uint32_t)(i + 4096), o0, o1);
    rrand[i]        = (int)(o0 & 63u);
    rrand[i + 4096] = (int)(o1 & 63u);
  }
#endif
}

// ---------------------------------------------------------------------------
// Prepass: split x into bf16 hi/lo  [B*T, EMB]
// ---------------------------------------------------------------------------
__global__ __launch_bounds__(256) void prep_x_split(
    const float* __restrict__ x, short* __restrict__ Xh, short* __restrict__ Xl) {
  size_t i8 = ((size_t)blockIdx.x * 256 + threadIdx.x) * 8;
  float4 v0 = *(const float4*)(x + i8);
  float4 v1 = *(const float4*)(x + i8 + 4);
  float f[8] = {v0.x, v0.y, v0.z, v0.w, v1.x, v1.y, v1.z, v1.w};
  short8v hh, ll;
#pragma unroll
  for (int j = 0; j < 8; j++) {
    short h = f2bf(f[j]);
    hh[j] = h;
    ll[j] = f2bf(f[j] - bf2f(h));
  }
  *(short8v*)(Xh + i8) = hh;
  *(short8v*)(Xl + i8) = ll;
}

// ---------------------------------------------------------------------------
// Prepass: transpose+split Wq/Wk/Wv [256,2048] -> Wt hi/lo [2048,256]
// ---------------------------------------------------------------------------
__global__ __launch_bounds__(256) void prep_w_split(
    const float* __restrict__ Wq, const float* __restrict__ Wk, const float* __restrict__ Wv,
    short* __restrict__ Qh, short* __restrict__ Ql,
    short* __restrict__ Kh, short* __restrict__ Kl,
    short* __restrict__ Vh, short* __restrict__ Vl) {
  const float* W; short *Oh, *Ol;
  if (blockIdx.z == 0)      { W = Wq; Oh = Qh; Ol = Ql; }
  else if (blockIdx.z == 1) { W = Wk; Oh = Kh; Ol = Kl; }
  else                      { W = Wv; Oh = Vh; Ol = Vl; }
  __shared__ float tile[32][33];
  const int tx = threadIdx.x & 31, trow = threadIdx.x >> 5;
  const int n0 = blockIdx.x * 32, k0 = blockIdx.y * 32;
#pragma unroll
  for (int i = 0; i < 4; i++) {
    int k = trow + i * 8;
    tile[k][tx] = W[(size_t)(k0 + k) * NQ + n0 + tx];
  }
  __syncthreads();
#pragma unroll
  for (int i = 0; i < 4; i++) {
    int n = trow + i * 8;
    float f = tile[tx][n];
    short h = f2bf(f);
    Oh[(size_t)(n0 + n) * EMB + k0 + tx] = h;
    Ol[(size_t)(n0 + n) * EMB + k0 + tx] = f2bf(f - bf2f(h));
  }
}

// ---------------------------------------------------------------------------
// Prepass: extract sel rows of x -> xsel (f32) + bf16 hi/lo splits
// ---------------------------------------------------------------------------
__global__ __launch_bounds__(256) void prep_sel(
    const float* __restrict__ x, float* __restrict__ xsel,
    short* __restrict__ xh, short* __restrict__ xl) {
  const int bp = blockIdx.x, b = bp >> 7, p = bp & 127;
  const int selp = STRIDE * p + STRIDE - 1;
  const int tid = threadIdx.x;
  float f = x[((size_t)b * TT + selp) * EMB + tid];
  xsel[(size_t)bp * EMB + tid] = f;
  short h = f2bf(f);
  xh[(size_t)bp * EMB + tid] = h;
  xl[(size_t)bp * EMB + tid] = f2bf(f - bf2f(h));
}

// ---------------------------------------------------------------------------
// Split-bf16 MFMA GEMM: C[M,2048] = scale * (A[M,256] @ W[256,2048])
// ---------------------------------------------------------------------------
__global__ __launch_bounds__(256) void gemm_split(
    const short* __restrict__ Ah_g, const short* __restrict__ Al_g,
    const short* __restrict__ B0h, const short* __restrict__ B0l,
    const short* __restrict__ B1h, const short* __restrict__ B1l,
    float* __restrict__ C0, float* __restrict__ C1, float scale)
{
  const short* Bh_g = (blockIdx.z == 0) ? B0h : B1h;
  const short* Bl_g = (blockIdx.z == 0) ? B0l : B1l;
  float* C = (blockIdx.z == 0) ? C0 : C1;

  const int tid = threadIdx.x;
  const int wid = tid >> 6, lane = tid & 63;
  const int wr = wid >> 1, wc = wid & 1;
  const int m0 = blockIdx.y * 128, n0 = blockIdx.x * 128;

  __shared__ __align__(16) short Ah[4096], Al[4096], Bh[4096], Bl[4096];

  const char* gbase;
  short* lbase;
  if (wid == 0)      { gbase = (const char*)(Ah_g) + (size_t)(m0 + lane) * 512; lbase = Ah; }
  else if (wid == 1) { gbase = (const char*)(Al_g) + (size_t)(m0 + lane) * 512; lbase = Al; }
  else if (wid == 2) { gbase = (const char*)(Bh_g) + (size_t)(n0 + lane) * 512; lbase = Bh; }
  else               { gbase = (const char*)(Bl_g) + (size_t)(n0 + lane) * 512; lbase = Bl; }

  float4v acc[4][4];
#pragma unroll
  for (int i = 0; i < 4; i++)
#pragma unroll
    for (int j = 0; j < 4; j++) acc[i][j] = (float4v)0.0f;

  const int aoff = (lane >> 4) * 1024 + (wr * 64 + (lane & 15)) * 8;
  const int boff = (lane >> 4) * 1024 + (wc * 64 + (lane & 15)) * 8;

  for (int ks = 0; ks < 8; ks++) {
    const int k0b = ks * 64;
#pragma unroll
    for (int c = 0; c < 8; c++) {
      const char* src = gbase + k0b + (c & 1) * (64 * 512) + (c >> 1) * 16;
      __builtin_amdgcn_global_load_lds(GLB_PTR(src), LDS_PTR(lbase + c * 512), 16, 0, 0);
    }
    __syncthreads();

    short8v ah[4], al[4], bh[4], bl[4];
#pragma unroll
    for (int mf = 0; mf < 4; mf++) {
      ah[mf] = *(const short8v*)(Ah + aoff + mf * 128);
      al[mf] = *(const short8v*)(Al + aoff + mf * 128);
    }
#pragma unroll
    for (int nf = 0; nf < 4; nf++) {
      bh[nf] = *(const short8v*)(Bh + boff + nf * 128);
      bl[nf] = *(const short8v*)(Bl + boff + nf * 128);
    }
#pragma unroll
    for (int mf = 0; mf < 4; mf++)
#pragma unroll
      for (int nf = 0; nf < 4; nf++) {
        acc[mf][nf] = __builtin_amdgcn_mfma_f32_16x16x32_bf16(ah[mf], bh[nf], acc[mf][nf], 0, 0, 0);
        acc[mf][nf] = __builtin_amdgcn_mfma_f32_16x16x32_bf16(ah[mf], bl[nf], acc[mf][nf], 0, 0, 0);
        acc[mf][nf] = __builtin_amdgcn_mfma_f32_16x16x32_bf16(al[mf], bh[nf], acc[mf][nf], 0, 0, 0);
      }
    __syncthreads();
  }

#pragma unroll
  for (int mf = 0; mf < 4; mf++) {
#pragma unroll
    for (int nf = 0; nf < 4; nf++) {
      int crow = m0 + wr * 64 + mf * 16 + (lane >> 4) * 4;
      int ccol = n0 + wc * 64 + nf * 16 + (lane & 15);
      float* cp = C + (size_t)crow * NQ + ccol;
#pragma unroll
      for (int r = 0; r < 4; r++)
        cp[(size_t)r * NQ] = acc[mf][nf][r] * scale;
    }
  }
}

// ---------------------------------------------------------------------------
// fp32 GEMM (MLP): C[M,N] = scale*(A[M,256] @ W[256,N])
// ---------------------------------------------------------------------------
__global__ __launch_bounds__(256) void gemm_k256(
    const float* __restrict__ A,
    const float* __restrict__ W0, const float* __restrict__ W1,
    float* __restrict__ C0, float* __restrict__ C1,
    int N, float scale)
{
  const float* W = (blockIdx.z == 0) ? W0 : W1;
  float* C = (blockIdx.z == 0) ? C0 : C1;

  const int tid = threadIdx.x;
  const int tx = tid & 15, ty = tid >> 4;
  const int m0 = blockIdx.y * 128, n0 = blockIdx.x * 128;

  __shared__ __align__(16) float AsT[16][128];
  __shared__ __align__(16) float Bs[16][128];

  float acc[8][8];
#pragma unroll
  for (int i = 0; i < 8; i++)
#pragma unroll
    for (int j = 0; j < 8; j++) acc[i][j] = 0.0f;

  for (int k0 = 0; k0 < EMB; k0 += 16) {
#pragma unroll
    for (int rep = 0; rep < 2; rep++) {
      int idx = rep * 1024 + tid * 4;
      int m = idx >> 4, kk = idx & 15;
      float4 v = *(const float4*)(A + (size_t)(m0 + m) * EMB + k0 + kk);
      AsT[kk + 0][m] = v.x; AsT[kk + 1][m] = v.y;
      AsT[kk + 2][m] = v.z; AsT[kk + 3][m] = v.w;
    }
#pragma unroll
    for (int rep = 0; rep < 2; rep++) {
      int idx = rep * 1024 + tid * 4;
      int kk = idx >> 7, n = idx & 127;
      *(float4*)(&Bs[kk][n]) = *(const float4*)(W + (size_t)(k0 + kk) * N + n0 + n);
    }
    __syncthreads();
#pragma unroll
    for (int kk = 0; kk < 16; kk++) {
      float a[8], bfr[8];
      *(float4*)&a[0] = *(const float4*)&AsT[kk][ty * 8];
      *(float4*)&a[4] = *(const float4*)&AsT[kk][ty * 8 + 4];
      *(float4*)&bfr[0] = *(const float4*)&Bs[kk][tx * 8];
      *(float4*)&bfr[4] = *(const float4*)&Bs[kk][tx * 8 + 4];
#pragma unroll
      for (int i = 0; i < 8; i++)
#pragma unroll
        for (int j = 0; j < 8; j++)
          acc[i][j] = fmaf(a[i], bfr[j], acc[i][j]);
    }
    __syncthreads();
  }
#pragma unroll
  for (int i = 0; i < 8; i++) {
    size_t row = (size_t)(m0 + ty * 8 + i);
    float* cp = C + row * N + n0 + tx * 8;
    float4 s0 = make_float4(acc[i][0] * scale, acc[i][1] * scale,
                            acc[i][2] * scale, acc[i][3] * scale);
    float4 s1 = make_float4(acc[i][4] * scale, acc[i][5] * scale,
                            acc[i][6] * scale, acc[i][7] * scale);
    *(float4*)cp = s0;
    *(float4*)(cp + 4) = s1;
  }
}

// ---------------------------------------------------------------------------
__device__ __forceinline__ float softplus_f(float v) {
  return fmaxf(v, 0.0f) + log1pf(expf(-fabsf(v)));
}

__global__ __launch_bounds__(256) void params2_kernel(
    const float* __restrict__ hid0,
    const float* __restrict__ W1,
    const float* __restrict__ b1,
    const float* __restrict__ W2,
    const float* __restrict__ b2,
    const int* __restrict__ grand, const int* __restrict__ rrand,
    int* __restrict__ idx_out, float* __restrict__ w_out)
{
  const int bp = blockIdx.x;
  const int b = bp >> 7, p = bp & 127;
  const int selp = STRIDE * p + STRIDE - 1;
  const int tid = threadIdx.x;
  const float coordp = (float)p / (float)TP;

  __shared__ float shid[HID];
  __shared__ float spartial[256];
  __shared__ float spar[2 * KMIX];
  __shared__ float sm[KMIX], ss[KMIX];
  __shared__ int   sidx[VS];
  __shared__ float sidxf[VS];
  __shared__ int   svalid[VS];
  __shared__ float sprops[KMIX][VS];
  __shared__ float sden[KMIX];

#pragma unroll
  for (int q = 0; q < HID / 256; q++) {
    int j = q * 256 + tid;
    shid[j] = fmaxf(hid0[(size_t)bp * HID + j] + coordp * W1[(size_t)EMB * HID + j] + b1[j], 0.0f);
  }
  __syncthreads();

  {
    int o = tid & 15, g = tid >> 4;
    float pa = 0.0f;
    for (int jj = 0; jj < 64; jj++) {
      int j = g * 64 + jj;
      pa = fmaf(shid[j], W2[j * (2 * KMIX) + o], pa);
    }
    spartial[o * 16 + g] = pa;
  }
  __syncthreads();
  if (tid < 2 * KMIX) {
    float acc = 0.0f;
    for (int g = 0; g < 16; g++) acc += spartial[tid * 16 + g];
    spar[tid] = acc + b2[tid];
  }
  __syncthreads();

  if (tid < KMIX) {
    float m = (float)selp - 3.0f * softplus_f(spar[tid]);
    m = fminf(fmaxf(m, 0.0f), (float)(TT - 1));
    sm[tid] = m;
    ss[tid] = (softplus_f(spar[KMIX + tid] + 2.0f) + 0.05f) * (float)TT * 0.1f;
  }
  __syncthreads();

  if (tid < VS) {
    int kk = tid / 6, jj = tid % 6;
    float fl = floorf(sm[kk]);
    float v;
    if (jj == 0) v = fl;
    else if (jj == 1) v = fl + 1.0f;
    else if (jj < 4) v = (float)grand[(bp * KMIX + kk) * GADD + (jj - 2)];
    else {
      float lo = fminf(fmaxf(fl - (float)(REGION / 2), 0.0f), (float)(TT - REGION));
      v = lo + (float)rrand[(bp * KMIX + kk) * RADD + (jj - 4)];
    }
    v = fminf(fmaxf(v, 0.0f), (float)(TT - 1));
    int ii = (int)v;
    sidx[tid] = ii;
    sidxf[tid] = (float)ii;
  }
  __syncthreads();

  if (tid < VS) {
    int d = 0;
    for (int u = 0; u < tid; u++) d |= (sidx[u] == sidx[tid]);
    svalid[tid] = (!d) && (sidx[tid] <= selp);
  }
  __syncthreads();

  for (int l = tid; l < KMIX * VS; l += 256) {
    int kk = l / VS, v = l - kk * VS;
    float z = (sidxf[v] - sm[kk]) / ss[kk];
    sprops[kk][v] = svalid[v] ? expf(-0.5f * z * z) : 0.0f;
  }
  __syncthreads();
  if (tid < KMIX) {
    float den = 0.0f;
    for (int v = 0; v < VS; v++) den += sprops[tid][v];
    sden[tid] = den;
  }
  __syncthreads();

  if (tid < VS) {
    float w = 0.0f;
    for (int kk = 0; kk < KMIX; kk++) w += sprops[kk][tid] / sden[kk];
    w_out[(size_t)bp * VS + tid] = w;
    idx_out[(size_t)bp * VS + tid] = sidx[tid];
  }
}

// ---------------------------------------------------------------------------
__global__ void fill_out(const float* __restrict__ bu, float* __restrict__ out, int total) {
  int i = blockIdx.x * 256 + threadIdx.x;
  if (i < total) out[i] = bu[i & (EMB - 1)];
}

// ---------------------------------------------------------------------------
// Attention phase 1, one block per (p, head) of one batch:
// gather-dot (per wave), softmax (wave 0), PV -> outp_all[bp][h*256+e].
// ---------------------------------------------------------------------------
__global__ __launch_bounds__(256) void attn2_kernel(
    const float* __restrict__ Qsel,  // [B*TP, NQ]
    const float* __restrict__ Kb,    // [T, NQ] this batch
    const float* __restrict__ Vb,    // [T, NQ]
    const int* __restrict__ idx_in,  // [B*TP, VS]
    const float* __restrict__ w_in,  // [B*TP, VS]
    float* __restrict__ outp_all,    // [B*TP, NQ]
    int b)
{
  const int p = blockIdx.x, h = blockIdx.y;
  const int bp = b * TP + p;
  const int tid = threadIdx.x;
  const int wave = tid >> 6, lane = tid & 63;

  __shared__ __align__(16) float q[EMB];
  __shared__ int   sidx[VS];
  __shared__ float sw[VS];
  __shared__ float sdot[VS];
  __shared__ float satt[VS];

  q[tid] = Qsel[(size_t)bp * NQ + h * 256 + tid];
  if (tid < VS) {
    sidx[tid] = idx_in[(size_t)bp * VS + tid];
    sw[tid]   = w_in[(size_t)bp * VS + tid];
  }
  __syncthreads();

  // dots: wave w handles v = w, w+4, ... (12 each); 64 lanes x 4 elems
  {
    float4 qq = *(const float4*)(q + lane * 4);
    for (int v = wave; v < VS; v += 4) {
      const float* kr = Kb + (size_t)sidx[v] * NQ + h * 256 + lane * 4;
      float4 kv = *(const float4*)kr;
      float par = qq.x * kv.x + qq.y * kv.y + qq.z * kv.z + qq.w * kv.w;
#pragma unroll
      for (int m = 32; m >= 1; m >>= 1) par += __shfl_xor(par, m, 64);
      if (lane == 0) sdot[v] = par;
    }
  }
  __syncthreads();

  // softmax on wave 0 (lanes 0..47 hold values)
  if (tid < 64) {
    float logit = (lane < VS) ? sw[lane] * sdot[lane] : -1e30f;
    float mx = logit;
#pragma unroll
    for (int m = 32; m >= 1; m >>= 1) mx = fmaxf(mx, __shfl_xor(mx, m, 64));
    float e = (lane < VS) ? __expf(logit - mx) : 0.0f;
    float sum = e;
#pragma unroll
    for (int m = 32; m >= 1; m >>= 1) sum += __shfl_xor(sum, m, 64);
    if (lane < VS) satt[lane] = e / sum;
  }
  __syncthreads();

  // PV: thread = output element e; 4 independent accumulators
  {
    float a0 = 0.f, a1 = 0.f, a2 = 0.f, a3 = 0.f;
#pragma unroll 4
    for (int v = 0; v < VS; v += 4) {
      a0 = fmaf(satt[v + 0], Vb[(size_t)sidx[v + 0] * NQ + h * 256 + tid], a0);
      a1 = fmaf(satt[v + 1], Vb[(size_t)sidx[v + 1] * NQ + h * 256 + tid], a1);
      a2 = fmaf(satt[v + 2], Vb[(size_t)sidx[v + 2] * NQ + h * 256 + tid], a2);
      a3 = fmaf(satt[v + 3], Vb[(size_t)sidx[v + 3] * NQ + h * 256 + tid], a3);
    }
    outp_all[(size_t)bp * NQ + h * 256 + tid] = (a0 + a1) + (a2 + a3);
  }
}

// ---------------------------------------------------------------------------
// Epilogue GEMM: out[sel rows] = outp_all[512,2048] @ Wu[2048,256] + bu.
// 64x64 tile, 256 threads (16x16, 4x4 each), BK=32.
// ---------------------------------------------------------------------------
__global__ __launch_bounds__(256) void epi_gemm(
    const float* __restrict__ outp,  // [512, NQ]
    const float* __restrict__ Wu,    // [NQ, EMB]
    const float* __restrict__ bu,
    float* __restrict__ out)         // [B, T, EMB]
{
  const int tid = threadIdx.x;
  const int tx = tid & 15, ty = tid >> 4;
  const int n0 = blockIdx.x * 64, m0 = blockIdx.y * 64;

  __shared__ float AsT[32][68];
  __shared__ __align__(16) float Bs[32][64];

  float acc[4][4];
#pragma unroll
  for (int i = 0; i < 4; i++)
#pragma unroll
    for (int j = 0; j < 4; j++) acc[i][j] = 0.0f;

  for (int k0 = 0; k0 < NQ; k0 += 32) {
#pragma unroll
    for (int r = 0; r < 2; r++) {
      int c = tid * 2 + r;            // 512 float4 chunks: A 64m x 32k
      int m = c >> 3, kq = c & 7;
      float4 v = *(const float4*)(outp + (size_t)(m0 + m) * NQ + k0 + kq * 4);
      AsT[kq * 4 + 0][m] = v.x; AsT[kq * 4 + 1][m] = v.y;
      AsT[kq * 4 + 2][m] = v.z; AsT[kq * 4 + 3][m] = v.w;
    }
#pragma unroll
    for (int r = 0; r < 2; r++) {
      int c = tid * 2 + r;            // B 32k x 64n
      int kk = c >> 4, n4 = c & 15;
      *(float4*)(&Bs[kk][n4 * 4]) =
          *(const float4*)(Wu + (size_t)(k0 + kk) * EMB + n0 + n4 * 4);
    }
    __syncthreads();
#pragma unroll
    for (int kk = 0; kk < 32; kk++) {
      float a[4], bfr[4];
      *(float4*)&a[0]  = *(const float4*)&AsT[kk][ty * 4];
      *(float4*)&bfr[0] = *(const float4*)&Bs[kk][tx * 4];
#pragma unroll
      for (int i = 0; i < 4; i++)
#pragma unroll
        for (int j = 0; j < 4; j++)
          acc[i][j] = fmaf(a[i], bfr[j], acc[i][j]);
    }
    __syncthreads();
  }

#pragma unroll
  for (int i = 0; i < 4; i++) {
    int bp = m0 + ty * 4 + i;
    int b = bp >> 7, p = bp & 127;
    int selp = STRIDE * p + STRIDE - 1;
    float* op = out + ((size_t)b * TT + selp) * EMB + n0 + tx * 4;
#pragma unroll
    for (int j = 0; j < 4; j++)
      op[j] = acc[i][j] + bu[n0 + tx * 4 + j];
  }
}

// ---------------------------------------------------------------------------
extern "C" void kernel_launch(void* const* d_in, const int* in_sizes, int n_in,
                              void* d_out, int out_size, void* d_ws, size_t ws_size,
                              hipStream_t stream) {
  const float* x  = (const float*)d_in[0];
  const float* Wq = (const float*)d_in[1];
  const float* Wk = (const float*)d_in[2];
  const float* Wv = (const float*)d_in[3];
  const float* Wu = (const float*)d_in[4];
  const float* bu = (const float*)d_in[5];
  const float* W1 = (const float*)d_in[6];
  const float* b1 = (const float*)d_in[7];
  const float* W2 = (const float*)d_in[8];
  const float* b2 = (const float*)d_in[9];
  float* out = (float*)d_out;

  // ---- workspace layout ----
  char* ws = (char*)d_ws;
  size_t off = 0;
  auto alloc = [&](size_t bytes) { char* p = ws + off; off += (bytes + 255) & ~(size_t)255; return p; };
  float* Kb    = (float*)alloc((size_t)TT * NQ * 4);        // 32 MB
  float* Vb    = (float*)alloc((size_t)TT * NQ * 4);        // 32 MB
  float* Qsel  = (float*)alloc((size_t)BB * TP * NQ * 4);   // 4 MB
  float* outp  = (float*)alloc((size_t)BB * TP * NQ * 4);   // 4 MB
  short* Xh    = (short*)alloc((size_t)BB * TT * EMB * 2);  // 8 MB
  short* Xl    = (short*)alloc((size_t)BB * TT * EMB * 2);  // 8 MB
  short* Wqth  = (short*)alloc((size_t)NQ * EMB * 2);
  short* Wqtl  = (short*)alloc((size_t)NQ * EMB * 2);
  short* Wkth  = (short*)alloc((size_t)NQ * EMB * 2);
  short* Wktl  = (short*)alloc((size_t)NQ * EMB * 2);
  short* Wvth  = (short*)alloc((size_t)NQ * EMB * 2);
  short* Wvtl  = (short*)alloc((size_t)NQ * EMB * 2);
  float* xsel  = (float*)alloc((size_t)BB * TP * EMB * 4);
  short* xselh = (short*)alloc((size_t)BB * TP * EMB * 2);
  short* xsell = (short*)alloc((size_t)BB * TP * EMB * 2);
  float* hid0  = (float*)alloc((size_t)BB * TP * HID * 4);  // 2 MB
  int*   idxb  = (int*)  alloc((size_t)BB * TP * VS * 4);
  float* wts   = (float*)alloc((size_t)BB * TP * VS * 4);
  int*   grand = (int*)  alloc((size_t)BB * TP * KMIX * GADD * 4);
  int*   rrand = (int*)  alloc((size_t)BB * TP * KMIX * RADD * 4);

  // 1. RNG + prepasses
  rand_kernel<<<dim3(32), dim3(256), 0, stream>>>(grand, rrand);
  prep_x_split<<<dim3((BB * TT * EMB) / (256 * 8)), dim3(256), 0, stream>>>(x, Xh, Xl);
  prep_w_split<<<dim3(NQ / 32, EMB / 32, 3), dim3(256), 0, stream>>>(
      Wq, Wk, Wv, Wqth, Wqtl, Wkth, Wktl, Wvth, Wvtl);
  prep_sel<<<dim3(BB * TP), dim3(256), 0, stream>>>(x, xsel, xselh, xsell);

  // 2. MLP gemm (fp32) + params finish
  gemm_k256<<<dim3(HID / 128, (BB * TP) / 128, 1), dim3(256), 0, stream>>>(
      xsel, W1, W1, hid0, hid0, HID, 1.0f);
  params2_kernel<<<dim3(BB * TP), dim3(256), 0, stream>>>(
      hid0, W1, b1, W2, b2, grand, rrand, idxb, wts);

  // 3. Q projection (split-bf16 MFMA); 1/16 folds both 1/e^0.25 factors
  gemm_split<<<dim3(NQ / 128, (BB * TP) / 128, 1), dim3(256), 0, stream>>>(
      xselh, xsell, Wqth, Wqtl, Wqth, Wqtl, Qsel, Qsel, 0.0625f);

  // 4. background output rows = bu
  fill_out<<<dim3((BB * TT * EMB) / 256), dim3(256), 0, stream>>>(
      bu, out, BB * TT * EMB);

  // 5. per-batch K/V projection (MFMA) + attention phase 1
  for (int b = 0; b < BB; b++) {
    const short* xbh = Xh + (size_t)b * TT * EMB;
    const short* xbl = Xl + (size_t)b * TT * EMB;
    gemm_split<<<dim3(NQ / 128, TT / 128, 2), dim3(256), 0, stream>>>(
        xbh, xbl, Wkth, Wktl, Wvth, Wvtl, Kb, Vb, 1.0f);
    attn2_kernel<<<dim3(TP, HEADS), dim3(256), 0, stream>>>(
        Qsel, Kb, Vb, idxb, wts, outp, b);
  }

  // 6. epilogue: out[sel] = outp @ Wu + bu
  epi_gemm<<<dim3(EMB / 64, (BB * TP) / 64), dim3(256), 0, stream>>>(
      outp, Wu, bu, out);
}

// Round 4
// 418.348 us; speedup vs baseline: 2.1179x; 1.2248x over previous
//
#include <hip/hip_runtime.h>
#include <stdint.h>

// ---------------------------------------------------------------------------
// Problem constants (from reference)
// ---------------------------------------------------------------------------
#define EMB   256
#define HEADS 8
#define KMIX  8
#define GADD  2
#define RADD  2
#define REGION 64
#define STRIDE 32
#define BB    4
#define TT    4096
#define TP    128
#define VS    48
#define HID   1024
#define NQ    2048

#define RNG_PARTITIONABLE 1

typedef short short8v __attribute__((ext_vector_type(8)));
typedef float float4v __attribute__((ext_vector_type(4)));

#define LDS_PTR(x) ((__attribute__((address_space(3))) void*)(x))
#define GLB_PTR(x) ((const __attribute__((address_space(1))) void*)(x))

// ---------------------------------------------------------------------------
// bf16 helpers (RNE)
// ---------------------------------------------------------------------------
__device__ __forceinline__ short f2bf(float f) {
  uint32_t u = __float_as_uint(f);
  u += 0x7FFFu + ((u >> 16) & 1u);
  return (short)(u >> 16);
}
__device__ __forceinline__ float bf2f(short h) {
  return __uint_as_float(((uint32_t)(uint16_t)h) << 16);
}

// ---------------------------------------------------------------------------
// Threefry-2x32 (JAX exact)
// ---------------------------------------------------------------------------
__device__ __forceinline__ uint32_t rotl32(uint32_t x, int d) {
  return (x << d) | (x >> (32 - d));
}
__device__ __forceinline__ void tf2x32(uint32_t k0, uint32_t k1,
                                       uint32_t x0, uint32_t x1,
                                       uint32_t& o0, uint32_t& o1) {
  uint32_t ks2 = k0 ^ k1 ^ 0x1BD11BDAu;
  x0 += k0; x1 += k1;
#define TFR(r) { x0 += x1; x1 = rotl32(x1, r); x1 ^= x0; }
  TFR(13) TFR(15) TFR(26) TFR(6)
  x0 += k1; x1 += ks2 + 1u;
  TFR(17) TFR(29) TFR(16) TFR(24)
  x0 += ks2; x1 += k0 + 2u;
  TFR(13) TFR(15) TFR(26) TFR(6)
  x0 += k0; x1 += k1 + 3u;
  TFR(17) TFR(29) TFR(16) TFR(24)
  x0 += k1; x1 += ks2 + 4u;
  TFR(13) TFR(15) TFR(26) TFR(6)
  x0 += ks2; x1 += k0 + 5u;
#undef TFR
  o0 = x0; o1 = x1;
}

__global__ void rand_kernel(int* __restrict__ grand, int* __restrict__ rrand) {
  int i = blockIdx.x * blockDim.x + threadIdx.x;
#if RNG_PARTITIONABLE
  uint32_t kg0, kg1, kr0, kr1;
  tf2x32(0u, 42u, 0u, 0u, kg0, kg1);
  tf2x32(0u, 42u, 0u, 1u, kr0, kr1);
  uint32_t g2k0, g2k1, r2k0, r2k1;
  tf2x32(kg0, kg1, 0u, 1u, g2k0, g2k1);
  tf2x32(kr0, kr1, 0u, 1u, r2k0, r2k1);
  if (i < BB * TP * KMIX * GADD) {
    uint32_t o0, o1;
    tf2x32(g2k0, g2k1, 0u, (uint32_t)i, o0, o1);
    grand[i] = (int)((o0 ^ o1) & 4095u);
    tf2x32(r2k0, r2k1, 0u, (uint32_t)i, o0, o1);
    rrand[i] = (int)((o0 ^ o1) & 63u);
  }
#else
  uint32_t a0, a1, b0, b1;
  tf2x32(0u, 42u, 0u, 2u, a0, a1);
  tf2x32(0u, 42u, 1u, 3u, b0, b1);
  uint32_t kg0 = a0, kg1 = b0, kr0 = a1, kr1 = b1;
  uint32_t c0, c1, d0, d1;
  tf2x32(kg0, kg1, 0u, 2u, c0, c1);
  tf2x32(kg0, kg1, 1u, 3u, d0, d1);
  uint32_t g2k0 = c1, g2k1 = d1;
  tf2x32(kr0, kr1, 0u, 2u, c0, c1);
  tf2x32(kr0, kr1, 1u, 3u, d0, d1);
  uint32_t r2k0 = c1, r2k1 = d1;
  if (i < 4096) {
    uint32_t o0, o1;
    tf2x32(g2k0, g2k1, (uint32_t)i, (uint32_t)(i + 4096), o0, o1);
    grand[i]        = (int)(o0 & 4095u);
    grand[i + 4096] = (int)(o1 & 4095u);
    tf2x32(r2k0, r2k1, (uint32_t)i, (uint32_t)(i + 4096), o0, o1);
    rrand[i]        = (int)(o0 & 63u);
    rrand[i + 4096] = (int)(o1 & 63u);
  }
#endif
}

// ---------------------------------------------------------------------------
// Prepass: split x into bf16 hi/lo  [B*T, EMB]
// ---------------------------------------------------------------------------
__global__ __launch_bounds__(256) void prep_x_split(
    const float* __restrict__ x, short* __restrict__ Xh, short* __restrict__ Xl) {
  size_t i8 = ((size_t)blockIdx.x * 256 + threadIdx.x) * 8;
  float4 v0 = *(const float4*)(x + i8);
  float4 v1 = *(const float4*)(x + i8 + 4);
  float f[8] = {v0.x, v0.y, v0.z, v0.w, v1.x, v1.y, v1.z, v1.w};
  short8v hh, ll;
#pragma unroll
  for (int j = 0; j < 8; j++) {
    short h = f2bf(f[j]);
    hh[j] = h;
    ll[j] = f2bf(f[j] - bf2f(h));
  }
  *(short8v*)(Xh + i8) = hh;
  *(short8v*)(Xl + i8) = ll;
}

// ---------------------------------------------------------------------------
// Prepass: transpose+split Wq/Wk/Wv [256,2048] -> Wt hi/lo [2048,256]
// ---------------------------------------------------------------------------
__global__ __launch_bounds__(256) void prep_w_split(
    const float* __restrict__ Wq, const float* __restrict__ Wk, const float* __restrict__ Wv,
    short* __restrict__ Qh, short* __restrict__ Ql,
    short* __restrict__ Kh, short* __restrict__ Kl,
    short* __restrict__ Vh, short* __restrict__ Vl) {
  const float* W; short *Oh, *Ol;
  if (blockIdx.z == 0)      { W = Wq; Oh = Qh; Ol = Ql; }
  else if (blockIdx.z == 1) { W = Wk; Oh = Kh; Ol = Kl; }
  else                      { W = Wv; Oh = Vh; Ol = Vl; }
  __shared__ float tile[32][33];
  const int tx = threadIdx.x & 31, trow = threadIdx.x >> 5;
  const int n0 = blockIdx.x * 32, k0 = blockIdx.y * 32;
#pragma unroll
  for (int i = 0; i < 4; i++) {
    int k = trow + i * 8;
    tile[k][tx] = W[(size_t)(k0 + k) * NQ + n0 + tx];
  }
  __syncthreads();
#pragma unroll
  for (int i = 0; i < 4; i++) {
    int n = trow + i * 8;
    float f = tile[tx][n];
    short h = f2bf(f);
    Oh[(size_t)(n0 + n) * EMB + k0 + tx] = h;
    Ol[(size_t)(n0 + n) * EMB + k0 + tx] = f2bf(f - bf2f(h));
  }
}

// ---------------------------------------------------------------------------
// Prepass: extract sel rows of x -> xsel (f32) + bf16 hi/lo splits
// ---------------------------------------------------------------------------
__global__ __launch_bounds__(256) void prep_sel(
    const float* __restrict__ x, float* __restrict__ xsel,
    short* __restrict__ xh, short* __restrict__ xl) {
  const int bp = blockIdx.x, b = bp >> 7, p = bp & 127;
  const int selp = STRIDE * p + STRIDE - 1;
  const int tid = threadIdx.x;
  float f = x[((size_t)b * TT + selp) * EMB + tid];
  xsel[(size_t)bp * EMB + tid] = f;
  short h = f2bf(f);
  xh[(size_t)bp * EMB + tid] = h;
  xl[(size_t)bp * EMB + tid] = f2bf(f - bf2f(h));
}

// ---------------------------------------------------------------------------
// Split-bf16 MFMA GEMM: C[M,2048] = scale * (A[M,256] @ W[256,2048])
// ---------------------------------------------------------------------------
__global__ __launch_bounds__(256) void gemm_split(
    const short* __restrict__ Ah_g, const short* __restrict__ Al_g,
    const short* __restrict__ B0h, const short* __restrict__ B0l,
    const short* __restrict__ B1h, const short* __restrict__ B1l,
    float* __restrict__ C0, float* __restrict__ C1, float scale)
{
  const short* Bh_g = (blockIdx.z == 0) ? B0h : B1h;
  const short* Bl_g = (blockIdx.z == 0) ? B0l : B1l;
  float* C = (blockIdx.z == 0) ? C0 : C1;

  const int tid = threadIdx.x;
  const int wid = tid >> 6, lane = tid & 63;
  const int wr = wid >> 1, wc = wid & 1;
  const int m0 = blockIdx.y * 128, n0 = blockIdx.x * 128;

  __shared__ __align__(16) short Ah[4096], Al[4096], Bh[4096], Bl[4096];

  const char* gbase;
  short* lbase;
  if (wid == 0)      { gbase = (const char*)(Ah_g) + (size_t)(m0 + lane) * 512; lbase = Ah; }
  else if (wid == 1) { gbase = (const char*)(Al_g) + (size_t)(m0 + lane) * 512; lbase = Al; }
  else if (wid == 2) { gbase = (const char*)(Bh_g) + (size_t)(n0 + lane) * 512; lbase = Bh; }
  else               { gbase = (const char*)(Bl_g) + (size_t)(n0 + lane) * 512; lbase = Bl; }

  float4v acc[4][4];
#pragma unroll
  for (int i = 0; i < 4; i++)
#pragma unroll
    for (int j = 0; j < 4; j++) acc[i][j] = (float4v)0.0f;

  const int aoff = (lane >> 4) * 1024 + (wr * 64 + (lane & 15)) * 8;
  const int boff = (lane >> 4) * 1024 + (wc * 64 + (lane & 15)) * 8;

  for (int ks = 0; ks < 8; ks++) {
    const int k0b = ks * 64;
#pragma unroll
    for (int c = 0; c < 8; c++) {
      const char* src = gbase + k0b + (c & 1) * (64 * 512) + (c >> 1) * 16;
      __builtin_amdgcn_global_load_lds(GLB_PTR(src), LDS_PTR(lbase + c * 512), 16, 0, 0);
    }
    __syncthreads();

    short8v ah[4], al[4], bh[4], bl[4];
#pragma unroll
    for (int mf = 0; mf < 4; mf++) {
      ah[mf] = *(const short8v*)(Ah + aoff + mf * 128);
      al[mf] = *(const short8v*)(Al + aoff + mf * 128);
    }
#pragma unroll
    for (int nf = 0; nf < 4; nf++) {
      bh[nf] = *(const short8v*)(Bh + boff + nf * 128);
      bl[nf] = *(const short8v*)(Bl + boff + nf * 128);
    }
#pragma unroll
    for (int mf = 0; mf < 4; mf++)
#pragma unroll
      for (int nf = 0; nf < 4; nf++) {
        acc[mf][nf] = __builtin_amdgcn_mfma_f32_16x16x32_bf16(ah[mf], bh[nf], acc[mf][nf], 0, 0, 0);
        acc[mf][nf] = __builtin_amdgcn_mfma_f32_16x16x32_bf16(ah[mf], bl[nf], acc[mf][nf], 0, 0, 0);
        acc[mf][nf] = __builtin_amdgcn_mfma_f32_16x16x32_bf16(al[mf], bh[nf], acc[mf][nf], 0, 0, 0);
      }
    __syncthreads();
  }

#pragma unroll
  for (int mf = 0; mf < 4; mf++) {
#pragma unroll
    for (int nf = 0; nf < 4; nf++) {
      int crow = m0 + wr * 64 + mf * 16 + (lane >> 4) * 4;
      int ccol = n0 + wc * 64 + nf * 16 + (lane & 15);
      float* cp = C + (size_t)crow * NQ + ccol;
#pragma unroll
      for (int r = 0; r < 4; r++)
        cp[(size_t)r * NQ] = acc[mf][nf][r] * scale;
    }
  }
}

// ---------------------------------------------------------------------------
// 64x64-tile fp32 GEMM over a K-chunk of 256.
// A[M, lda] (row-major), W[K, ldw] (row-major), writes C + z*cstride,
// C[m][n] with row stride ldc. grid = (N/64, M/64, KCHUNKS).
// ---------------------------------------------------------------------------
__global__ __launch_bounds__(256) void gemm64_f32(
    const float* __restrict__ A, int lda,
    const float* __restrict__ W, int ldw,
    float* __restrict__ C, int ldc, size_t cstride)
{
  const int tid = threadIdx.x;
  const int tx = tid & 15, ty = tid >> 4;
  const int n0 = blockIdx.x * 64, m0 = blockIdx.y * 64;
  const int kb = blockIdx.z * 256;
  C += (size_t)blockIdx.z * cstride;

  __shared__ float As[64][36];                 // row-major A tile, padded
  __shared__ __align__(16) float Bs[32][64];

  float acc[4][4];
#pragma unroll
  for (int i = 0; i < 4; i++)
#pragma unroll
    for (int j = 0; j < 4; j++) acc[i][j] = 0.0f;

  for (int k0 = kb; k0 < kb + 256; k0 += 32) {
    {
      int c = tid * 2;                          // A: 64 rows x 32 k, 512 float4
      int r = c >> 3, kq = c & 7;
      float4 v0 = *(const float4*)(A + (size_t)(m0 + r) * lda + k0 + kq * 4);
      float4 v1 = *(const float4*)(A + (size_t)(m0 + r) * lda + k0 + (kq + 1) * 4);
      As[r][kq * 4 + 0] = v0.x; As[r][kq * 4 + 1] = v0.y;
      As[r][kq * 4 + 2] = v0.z; As[r][kq * 4 + 3] = v0.w;
      As[r][kq * 4 + 4] = v1.x; As[r][kq * 4 + 5] = v1.y;
      As[r][kq * 4 + 6] = v1.z; As[r][kq * 4 + 7] = v1.w;
    }
    {
      int c = tid * 2;                          // B: 32 k x 64 n, 512 float4
      int kk = c >> 4, n4 = c & 15;
      *(float4*)(&Bs[kk][n4 * 4]) = *(const float4*)(W + (size_t)(k0 + kk) * ldw + n0 + n4 * 4);
      *(float4*)(&Bs[kk][n4 * 4 + 4]) = *(const float4*)(W + (size_t)(k0 + kk) * ldw + n0 + n4 * 4 + 4);
    }
    __syncthreads();
#pragma unroll
    for (int kk = 0; kk < 32; kk++) {
      float a[4], bfr[4];
#pragma unroll
      for (int i = 0; i < 4; i++) a[i] = As[ty * 4 + i][kk];
      *(float4*)&bfr[0] = *(const float4*)&Bs[kk][tx * 4];
#pragma unroll
      for (int i = 0; i < 4; i++)
#pragma unroll
        for (int j = 0; j < 4; j++)
          acc[i][j] = fmaf(a[i], bfr[j], acc[i][j]);
    }
    __syncthreads();
  }

#pragma unroll
  for (int i = 0; i < 4; i++) {
    float* cp = C + (size_t)(m0 + ty * 4 + i) * ldc + n0 + tx * 4;
    *(float4*)cp = make_float4(acc[i][0], acc[i][1], acc[i][2], acc[i][3]);
  }
}

// Reduce split-K partials + bias, scatter to sel rows.
__global__ __launch_bounds__(256) void epi_reduce(
    const float* __restrict__ partial,  // [8][512][256]
    const float* __restrict__ bu,
    float* __restrict__ out)
{
  const int bp = blockIdx.x, e = threadIdx.x;
  const int b = bp >> 7, p = bp & 127;
  const int selp = STRIDE * p + STRIDE - 1;
  float s = bu[e];
#pragma unroll
  for (int z = 0; z < 8; z++)
    s += partial[((size_t)z * (BB * TP) + bp) * EMB + e];
  out[((size_t)b * TT + selp) * EMB + e] = s;
}

// ---------------------------------------------------------------------------
__device__ __forceinline__ float softplus_f(float v) {
  return fmaxf(v, 0.0f) + log1pf(expf(-fabsf(v)));
}

__global__ __launch_bounds__(256) void params2_kernel(
    const float* __restrict__ hid0,
    const float* __restrict__ W1,
    const float* __restrict__ b1,
    const float* __restrict__ W2,
    const float* __restrict__ b2,
    const int* __restrict__ grand, const int* __restrict__ rrand,
    int* __restrict__ idx_out, float* __restrict__ w_out)
{
  const int bp = blockIdx.x;
  const int b = bp >> 7, p = bp & 127;
  const int selp = STRIDE * p + STRIDE - 1;
  const int tid = threadIdx.x;
  const float coordp = (float)p / (float)TP;

  __shared__ float shid[HID];
  __shared__ float spartial[256];
  __shared__ float spar[2 * KMIX];
  __shared__ float sm[KMIX], ss[KMIX];
  __shared__ int   sidx[VS];
  __shared__ float sidxf[VS];
  __shared__ int   svalid[VS];
  __shared__ float sprops[KMIX][VS];
  __shared__ float sden[KMIX];

#pragma unroll
  for (int q = 0; q < HID / 256; q++) {
    int j = q * 256 + tid;
    shid[j] = fmaxf(hid0[(size_t)bp * HID + j] + coordp * W1[(size_t)EMB * HID + j] + b1[j], 0.0f);
  }
  __syncthreads();

  {
    int o = tid & 15, g = tid >> 4;
    float pa = 0.0f;
    for (int jj = 0; jj < 64; jj++) {
      int j = g * 64 + jj;
      pa = fmaf(shid[j], W2[j * (2 * KMIX) + o], pa);
    }
    spartial[o * 16 + g] = pa;
  }
  __syncthreads();
  if (tid < 2 * KMIX) {
    float acc = 0.0f;
    for (int g = 0; g < 16; g++) acc += spartial[tid * 16 + g];
    spar[tid] = acc + b2[tid];
  }
  __syncthreads();

  if (tid < KMIX) {
    float m = (float)selp - 3.0f * softplus_f(spar[tid]);
    m = fminf(fmaxf(m, 0.0f), (float)(TT - 1));
    sm[tid] = m;
    ss[tid] = (softplus_f(spar[KMIX + tid] + 2.0f) + 0.05f) * (float)TT * 0.1f;
  }
  __syncthreads();

  if (tid < VS) {
    int kk = tid / 6, jj = tid % 6;
    float fl = floorf(sm[kk]);
    float v;
    if (jj == 0) v = fl;
    else if (jj == 1) v = fl + 1.0f;
    else if (jj < 4) v = (float)grand[(bp * KMIX + kk) * GADD + (jj - 2)];
    else {
      float lo = fminf(fmaxf(fl - (float)(REGION / 2), 0.0f), (float)(TT - REGION));
      v = lo + (float)rrand[(bp * KMIX + kk) * RADD + (jj - 4)];
    }
    v = fminf(fmaxf(v, 0.0f), (float)(TT - 1));
    int ii = (int)v;
    sidx[tid] = ii;
    sidxf[tid] = (float)ii;
  }
  __syncthreads();

  if (tid < VS) {
    int d = 0;
    for (int u = 0; u < tid; u++) d |= (sidx[u] == sidx[tid]);
    svalid[tid] = (!d) && (sidx[tid] <= selp);
  }
  __syncthreads();

  for (int l = tid; l < KMIX * VS; l += 256) {
    int kk = l / VS, v = l - kk * VS;
    float z = (sidxf[v] - sm[kk]) / ss[kk];
    sprops[kk][v] = svalid[v] ? expf(-0.5f * z * z) : 0.0f;
  }
  __syncthreads();
  if (tid < KMIX) {
    float den = 0.0f;
    for (int v = 0; v < VS; v++) den += sprops[tid][v];
    sden[tid] = den;
  }
  __syncthreads();

  if (tid < VS) {
    float w = 0.0f;
    for (int kk = 0; kk < KMIX; kk++) w += sprops[kk][tid] / sden[kk];
    w_out[(size_t)bp * VS + tid] = w;
    idx_out[(size_t)bp * VS + tid] = sidx[tid];
  }
}

// ---------------------------------------------------------------------------
__global__ void fill_out(const float* __restrict__ bu, float* __restrict__ out, int total) {
  int i = blockIdx.x * 256 + threadIdx.x;
  if (i < total) out[i] = bu[i & (EMB - 1)];
}

// ---------------------------------------------------------------------------
// Attention phase 1, one block per (p, head) of one batch.
// ---------------------------------------------------------------------------
__global__ __launch_bounds__(256) void attn2_kernel(
    const float* __restrict__ Qsel,  // [B*TP, NQ]
    const float* __restrict__ Kb,    // [T, NQ] this batch
    const float* __restrict__ Vb,    // [T, NQ]
    const int* __restrict__ idx_in,  // [B*TP, VS]
    const float* __restrict__ w_in,  // [B*TP, VS]
    float* __restrict__ outp_all,    // [B*TP, NQ]
    int b)
{
  const int p = blockIdx.x, h = blockIdx.y;
  const int bp = b * TP + p;
  const int tid = threadIdx.x;
  const int wave = tid >> 6, lane = tid & 63;

  __shared__ __align__(16) float q[EMB];
  __shared__ int   sidx[VS];
  __shared__ float sw[VS];
  __shared__ float sdot[VS];
  __shared__ float satt[VS];

  q[tid] = Qsel[(size_t)bp * NQ + h * 256 + tid];
  if (tid < VS) {
    sidx[tid] = idx_in[(size_t)bp * VS + tid];
    sw[tid]   = w_in[(size_t)bp * VS + tid];
  }
  __syncthreads();

  {
    float4 qq = *(const float4*)(q + lane * 4);
    for (int v = wave; v < VS; v += 4) {
      const float* kr = Kb + (size_t)sidx[v] * NQ + h * 256 + lane * 4;
      float4 kv = *(const float4*)kr;
      float par = qq.x * kv.x + qq.y * kv.y + qq.z * kv.z + qq.w * kv.w;
#pragma unroll
      for (int m = 32; m >= 1; m >>= 1) par += __shfl_xor(par, m, 64);
      if (lane == 0) sdot[v] = par;
    }
  }
  __syncthreads();

  if (tid < 64) {
    float logit = (lane < VS) ? sw[lane] * sdot[lane] : -1e30f;
    float mx = logit;
#pragma unroll
    for (int m = 32; m >= 1; m >>= 1) mx = fmaxf(mx, __shfl_xor(mx, m, 64));
    float e = (lane < VS) ? __expf(logit - mx) : 0.0f;
    float sum = e;
#pragma unroll
    for (int m = 32; m >= 1; m >>= 1) sum += __shfl_xor(sum, m, 64);
    if (lane < VS) satt[lane] = e / sum;
  }
  __syncthreads();

  {
    float a0 = 0.f, a1 = 0.f, a2 = 0.f, a3 = 0.f;
#pragma unroll 4
    for (int v = 0; v < VS; v += 4) {
      a0 = fmaf(satt[v + 0], Vb[(size_t)sidx[v + 0] * NQ + h * 256 + tid], a0);
      a1 = fmaf(satt[v + 1], Vb[(size_t)sidx[v + 1] * NQ + h * 256 + tid], a1);
      a2 = fmaf(satt[v + 2], Vb[(size_t)sidx[v + 2] * NQ + h * 256 + tid], a2);
      a3 = fmaf(satt[v + 3], Vb[(size_t)sidx[v + 3] * NQ + h * 256 + tid], a3);
    }
    outp_all[(size_t)bp * NQ + h * 256 + tid] = (a0 + a1) + (a2 + a3);
  }
}

// ---------------------------------------------------------------------------
extern "C" void kernel_launch(void* const* d_in, const int* in_sizes, int n_in,
                              void* d_out, int out_size, void* d_ws, size_t ws_size,
                              hipStream_t stream) {
  const float* x  = (const float*)d_in[0];
  const float* Wq = (const float*)d_in[1];
  const float* Wk = (const float*)d_in[2];
  const float* Wv = (const float*)d_in[3];
  const float* Wu = (const float*)d_in[4];
  const float* bu = (const float*)d_in[5];
  const float* W1 = (const float*)d_in[6];
  const float* b1 = (const float*)d_in[7];
  const float* W2 = (const float*)d_in[8];
  const float* b2 = (const float*)d_in[9];
  float* out = (float*)d_out;

  // ---- workspace layout ----
  char* ws = (char*)d_ws;
  size_t off = 0;
  auto alloc = [&](size_t bytes) { char* p = ws + off; off += (bytes + 255) & ~(size_t)255; return p; };
  float* Kb    = (float*)alloc((size_t)TT * NQ * 4);        // 32 MB
  float* Vb    = (float*)alloc((size_t)TT * NQ * 4);        // 32 MB
  float* Qsel  = (float*)alloc((size_t)BB * TP * NQ * 4);   // 4 MB
  float* outp  = (float*)alloc((size_t)BB * TP * NQ * 4);   // 4 MB
  float* part  = (float*)alloc((size_t)8 * BB * TP * EMB * 4); // 4 MB
  short* Xh    = (short*)alloc((size_t)BB * TT * EMB * 2);  // 8 MB
  short* Xl    = (short*)alloc((size_t)BB * TT * EMB * 2);  // 8 MB
  short* Wqth  = (short*)alloc((size_t)NQ * EMB * 2);
  short* Wqtl  = (short*)alloc((size_t)NQ * EMB * 2);
  short* Wkth  = (short*)alloc((size_t)NQ * EMB * 2);
  short* Wktl  = (short*)alloc((size_t)NQ * EMB * 2);
  short* Wvth  = (short*)alloc((size_t)NQ * EMB * 2);
  short* Wvtl  = (short*)alloc((size_t)NQ * EMB * 2);
  float* xsel  = (float*)alloc((size_t)BB * TP * EMB * 4);
  short* xselh = (short*)alloc((size_t)BB * TP * EMB * 2);
  short* xsell = (short*)alloc((size_t)BB * TP * EMB * 2);
  float* hid0  = (float*)alloc((size_t)BB * TP * HID * 4);  // 2 MB
  int*   idxb  = (int*)  alloc((size_t)BB * TP * VS * 4);
  float* wts   = (float*)alloc((size_t)BB * TP * VS * 4);
  int*   grand = (int*)  alloc((size_t)BB * TP * KMIX * GADD * 4);
  int*   rrand = (int*)  alloc((size_t)BB * TP * KMIX * RADD * 4);

  // 1. RNG + prepasses
  rand_kernel<<<dim3(32), dim3(256), 0, stream>>>(grand, rrand);
  prep_x_split<<<dim3((BB * TT * EMB) / (256 * 8)), dim3(256), 0, stream>>>(x, Xh, Xl);
  prep_w_split<<<dim3(NQ / 32, EMB / 32, 3), dim3(256), 0, stream>>>(
      Wq, Wk, Wv, Wqth, Wqtl, Wkth, Wktl, Wvth, Wvtl);
  prep_sel<<<dim3(BB * TP), dim3(256), 0, stream>>>(x, xsel, xselh, xsell);

  // 2. MLP gemm (fp32, 64x64 tiles) + params finish
  gemm64_f32<<<dim3(HID / 64, (BB * TP) / 64, 1), dim3(256), 0, stream>>>(
      xsel, EMB, W1, HID, hid0, HID, 0);
  params2_kernel<<<dim3(BB * TP), dim3(256), 0, stream>>>(
      hid0, W1, b1, W2, b2, grand, rrand, idxb, wts);

  // 3. Q projection (split-bf16 MFMA); 1/16 folds both 1/e^0.25 factors
  gemm_split<<<dim3(NQ / 128, (BB * TP) / 128, 1), dim3(256), 0, stream>>>(
      xselh, xsell, Wqth, Wqtl, Wqth, Wqtl, Qsel, Qsel, 0.0625f);

  // 4. background output rows = bu
  fill_out<<<dim3((BB * TT * EMB) / 256), dim3(256), 0, stream>>>(
      bu, out, BB * TT * EMB);

  // 5. per-batch K/V projection (MFMA) + attention phase 1
  for (int b = 0; b < BB; b++) {
    const short* xbh = Xh + (size_t)b * TT * EMB;
    const short* xbl = Xl + (size_t)b * TT * EMB;
    gemm_split<<<dim3(NQ / 128, TT / 128, 2), dim3(256), 0, stream>>>(
        xbh, xbl, Wkth, Wktl, Wvth, Wvtl, Kb, Vb, 1.0f);
    attn2_kernel<<<dim3(TP, HEADS), dim3(256), 0, stream>>>(
        Qsel, Kb, Vb, idxb, wts, outp, b);
  }

  // 6. epilogue: split-K GEMM (outp @ Wu) then reduce + bias + scatter
  gemm64_f32<<<dim3(EMB / 64, (BB * TP) / 64, NQ / 256), dim3(256), 0, stream>>>(
      outp, NQ, Wu, EMB, part, EMB, (size_t)BB * TP * EMB);
  epi_reduce<<<dim3(BB * TP), dim3(256), 0, stream>>>(part, bu, out);
}

// Round 5
// 340.417 us; speedup vs baseline: 2.6027x; 1.2289x over previous
//
#include <hip/hip_runtime.h>
#include <stdint.h>

// ---------------------------------------------------------------------------
// Problem constants (from reference)
// ---------------------------------------------------------------------------
#define EMB   256
#define HEADS 8
#define KMIX  8
#define GADD  2
#define RADD  2
#define REGION 64
#define STRIDE 32
#define BB    4
#define TT    4096
#define TP    128
#define VS    48
#define HID   1024
#define NQ    2048

#define RNG_PARTITIONABLE 1

typedef short short8v __attribute__((ext_vector_type(8)));
typedef float float4v __attribute__((ext_vector_type(4)));

#define LDS_PTR(x) ((__attribute__((address_space(3))) void*)(x))
#define GLB_PTR(x) ((const __attribute__((address_space(1))) void*)(x))

// ---------------------------------------------------------------------------
// bf16 helpers (RNE)
// ---------------------------------------------------------------------------
__device__ __forceinline__ short f2bf(float f) {
  uint32_t u = __float_as_uint(f);
  u += 0x7FFFu + ((u >> 16) & 1u);
  return (short)(u >> 16);
}
__device__ __forceinline__ float bf2f(short h) {
  return __uint_as_float(((uint32_t)(uint16_t)h) << 16);
}

// ---------------------------------------------------------------------------
// Threefry-2x32 (JAX exact)
// ---------------------------------------------------------------------------
__device__ __forceinline__ uint32_t rotl32(uint32_t x, int d) {
  return (x << d) | (x >> (32 - d));
}
__device__ __forceinline__ void tf2x32(uint32_t k0, uint32_t k1,
                                       uint32_t x0, uint32_t x1,
                                       uint32_t& o0, uint32_t& o1) {
  uint32_t ks2 = k0 ^ k1 ^ 0x1BD11BDAu;
  x0 += k0; x1 += k1;
#define TFR(r) { x0 += x1; x1 = rotl32(x1, r); x1 ^= x0; }
  TFR(13) TFR(15) TFR(26) TFR(6)
  x0 += k1; x1 += ks2 + 1u;
  TFR(17) TFR(29) TFR(16) TFR(24)
  x0 += ks2; x1 += k0 + 2u;
  TFR(13) TFR(15) TFR(26) TFR(6)
  x0 += k0; x1 += k1 + 3u;
  TFR(17) TFR(29) TFR(16) TFR(24)
  x0 += k1; x1 += ks2 + 4u;
  TFR(13) TFR(15) TFR(26) TFR(6)
  x0 += ks2; x1 += k0 + 5u;
#undef TFR
  o0 = x0; o1 = x1;
}

__global__ void rand_kernel(int* __restrict__ grand, int* __restrict__ rrand) {
  int i = blockIdx.x * blockDim.x + threadIdx.x;
#if RNG_PARTITIONABLE
  uint32_t kg0, kg1, kr0, kr1;
  tf2x32(0u, 42u, 0u, 0u, kg0, kg1);
  tf2x32(0u, 42u, 0u, 1u, kr0, kr1);
  uint32_t g2k0, g2k1, r2k0, r2k1;
  tf2x32(kg0, kg1, 0u, 1u, g2k0, g2k1);
  tf2x32(kr0, kr1, 0u, 1u, r2k0, r2k1);
  if (i < BB * TP * KMIX * GADD) {
    uint32_t o0, o1;
    tf2x32(g2k0, g2k1, 0u, (uint32_t)i, o0, o1);
    grand[i] = (int)((o0 ^ o1) & 4095u);
    tf2x32(r2k0, r2k1, 0u, (uint32_t)i, o0, o1);
    rrand[i] = (int)((o0 ^ o1) & 63u);
  }
#else
  uint32_t a0, a1, b0, b1;
  tf2x32(0u, 42u, 0u, 2u, a0, a1);
  tf2x32(0u, 42u, 1u, 3u, b0, b1);
  uint32_t kg0 = a0, kg1 = b0, kr0 = a1, kr1 = b1;
  uint32_t c0, c1, d0, d1;
  tf2x32(kg0, kg1, 0u, 2u, c0, c1);
  tf2x32(kg0, kg1, 1u, 3u, d0, d1);
  uint32_t g2k0 = c1, g2k1 = d1;
  tf2x32(kr0, kr1, 0u, 2u, c0, c1);
  tf2x32(kr0, kr1, 1u, 3u, d0, d1);
  uint32_t r2k0 = c1, r2k1 = d1;
  if (i < 4096) {
    uint32_t o0, o1;
    tf2x32(g2k0, g2k1, (uint32_t)i, (uint32_t)(i + 4096), o0, o1);
    grand[i]        = (int)(o0 & 4095u);
    grand[i + 4096] = (int)(o1 & 4095u);
    tf2x32(r2k0, r2k1, (uint32_t)i, (uint32_t)(i + 4096), o0, o1);
    rrand[i]        = (int)(o0 & 63u);
    rrand[i + 4096] = (int)(o1 & 63u);
  }
#endif
}

// ---------------------------------------------------------------------------
// Prepass: x -> bf16 hi  [B*T, EMB]   (lo split no longer needed: 2-term GEMM)
// ---------------------------------------------------------------------------
__global__ __launch_bounds__(256) void prep_x_hi(
    const float* __restrict__ x, short* __restrict__ Xh) {
  size_t i8 = ((size_t)blockIdx.x * 256 + threadIdx.x) * 8;
  float4 v0 = *(const float4*)(x + i8);
  float4 v1 = *(const float4*)(x + i8 + 4);
  float f[8] = {v0.x, v0.y, v0.z, v0.w, v1.x, v1.y, v1.z, v1.w};
  short8v hh;
#pragma unroll
  for (int j = 0; j < 8; j++) hh[j] = f2bf(f[j]);
  *(short8v*)(Xh + i8) = hh;
}

// ---------------------------------------------------------------------------
// Prepass: transpose+split Wq/Wk/Wv [256,2048] -> Wt hi/lo [2048,256]
// ---------------------------------------------------------------------------
__global__ __launch_bounds__(256) void prep_w_split(
    const float* __restrict__ Wq, const float* __restrict__ Wk, const float* __restrict__ Wv,
    short* __restrict__ Qh, short* __restrict__ Ql,
    short* __restrict__ Kh, short* __restrict__ Kl,
    short* __restrict__ Vh, short* __restrict__ Vl) {
  const float* W; short *Oh, *Ol;
  if (blockIdx.z == 0)      { W = Wq; Oh = Qh; Ol = Ql; }
  else if (blockIdx.z == 1) { W = Wk; Oh = Kh; Ol = Kl; }
  else                      { W = Wv; Oh = Vh; Ol = Vl; }
  __shared__ float tile[32][33];
  const int tx = threadIdx.x & 31, trow = threadIdx.x >> 5;
  const int n0 = blockIdx.x * 32, k0 = blockIdx.y * 32;
#pragma unroll
  for (int i = 0; i < 4; i++) {
    int k = trow + i * 8;
    tile[k][tx] = W[(size_t)(k0 + k) * NQ + n0 + tx];
  }
  __syncthreads();
#pragma unroll
  for (int i = 0; i < 4; i++) {
    int n = trow + i * 8;
    float f = tile[tx][n];
    short h = f2bf(f);
    Oh[(size_t)(n0 + n) * EMB + k0 + tx] = h;
    Ol[(size_t)(n0 + n) * EMB + k0 + tx] = f2bf(f - bf2f(h));
  }
}

// ---------------------------------------------------------------------------
// Prepass: extract sel rows of x -> xsel (f32) + bf16 hi
// ---------------------------------------------------------------------------
__global__ __launch_bounds__(256) void prep_sel(
    const float* __restrict__ x, float* __restrict__ xsel,
    short* __restrict__ xh) {
  const int bp = blockIdx.x, b = bp >> 7, p = bp & 127;
  const int selp = STRIDE * p + STRIDE - 1;
  const int tid = threadIdx.x;
  float f = x[((size_t)b * TT + selp) * EMB + tid];
  xsel[(size_t)bp * EMB + tid] = f;
  xh[(size_t)bp * EMB + tid] = f2bf(f);
}

// ---------------------------------------------------------------------------
// 2-term split-bf16 MFMA GEMM, 2-phase prefetch schedule:
//   C[M,2048] = scale * (Ah @ (Bh + Bl))        (error ~ x_lo*W ~ 2^-9 rel)
// A hi bf16 [M,256]; W TRANSPOSED hi/lo bf16 [2048,256].
// 128x128 tile, BK=32, 4 waves (2x2), double-buffered LDS (48KB),
// one barrier per K-step; prefetch of step k+1 issued before compute of k.
// ---------------------------------------------------------------------------
__global__ __launch_bounds__(256) void gemm_split2(
    const short* __restrict__ Ah_g,
    const short* __restrict__ B0h, const short* __restrict__ B0l,
    const short* __restrict__ B1h, const short* __restrict__ B1l,
    float* __restrict__ C0, float* __restrict__ C1, float scale)
{
  const short* Bh_g = (blockIdx.z == 0) ? B0h : B1h;
  const short* Bl_g = (blockIdx.z == 0) ? B0l : B1l;
  float* C = (blockIdx.z == 0) ? C0 : C1;

  const int tid = threadIdx.x;
  const int wid = tid >> 6, lane = tid & 63;
  const int wr = wid >> 1, wc = wid & 1;
  const int m0 = blockIdx.y * 128, n0 = blockIdx.x * 128;

  __shared__ __align__(16) short Ah[2 * 4096], Bh[2 * 4096], Bl[2 * 4096];

  // staging assignment: wave 0 -> Ah, wave 1 -> Bh, wave 2 -> Bl, wave 3 idle
  const char* gbase = nullptr;
  short* lbase = nullptr;
  if (wid == 0)      { gbase = (const char*)(Ah_g) + (size_t)(m0 + lane) * 512; lbase = Ah; }
  else if (wid == 1) { gbase = (const char*)(Bh_g) + (size_t)(n0 + lane) * 512; lbase = Bh; }
  else if (wid == 2) { gbase = (const char*)(Bl_g) + (size_t)(n0 + lane) * 512; lbase = Bl; }

  float4v acc[4][4];
#pragma unroll
  for (int i = 0; i < 4; i++)
#pragma unroll
    for (int j = 0; j < 4; j++) acc[i][j] = (float4v)0.0f;

  const int aoff = (lane >> 4) * 1024 + (wr * 64 + (lane & 15)) * 8;
  const int boff = (lane >> 4) * 1024 + (wc * 64 + (lane & 15)) * 8;

  auto stage = [&](int ks, int d) {
    if (wid < 3) {
      const char* g = gbase + ks * 64;
      short* l = lbase + d * 4096;
#pragma unroll
      for (int c = 0; c < 8; c++) {
        __builtin_amdgcn_global_load_lds(
            GLB_PTR(g + (c & 1) * (64 * 512) + (c >> 1) * 16),
            LDS_PTR(l + c * 512), 16, 0, 0);
      }
    }
  };

  stage(0, 0);
  __syncthreads();

  for (int ks = 0; ks < 8; ks++) {
    const int cur = ks & 1;
    if (ks < 7) stage(ks + 1, cur ^ 1);   // prefetch overlaps this step's MFMA

    const int cb = cur * 4096;
    short8v ah[4], bh[4], bl[4];
#pragma unroll
    for (int mf = 0; mf < 4; mf++)
      ah[mf] = *(const short8v*)(Ah + cb + aoff + mf * 128);
#pragma unroll
    for (int nf = 0; nf < 4; nf++) {
      bh[nf] = *(const short8v*)(Bh + cb + boff + nf * 128);
      bl[nf] = *(const short8v*)(Bl + cb + boff + nf * 128);
    }
#pragma unroll
    for (int mf = 0; mf < 4; mf++)
#pragma unroll
      for (int nf = 0; nf < 4; nf++) {
        acc[mf][nf] = __builtin_amdgcn_mfma_f32_16x16x32_bf16(ah[mf], bh[nf], acc[mf][nf], 0, 0, 0);
        acc[mf][nf] = __builtin_amdgcn_mfma_f32_16x16x32_bf16(ah[mf], bl[nf], acc[mf][nf], 0, 0, 0);
      }
    __syncthreads();   // drains prefetch loads (overlapped) + protects LDS reuse
  }

  // epilogue: C/D layout col=lane&15, row=(lane>>4)*4+r
#pragma unroll
  for (int mf = 0; mf < 4; mf++) {
#pragma unroll
    for (int nf = 0; nf < 4; nf++) {
      int crow = m0 + wr * 64 + mf * 16 + (lane >> 4) * 4;
      int ccol = n0 + wc * 64 + nf * 16 + (lane & 15);
      float* cp = C + (size_t)crow * NQ + ccol;
#pragma unroll
      for (int r = 0; r < 4; r++)
        cp[(size_t)r * NQ] = acc[mf][nf][r] * scale;
    }
  }
}

// ---------------------------------------------------------------------------
// 64x64-tile fp32 GEMM over a K-chunk of 256.  grid = (N/64, M/64, KCHUNKS).
// ---------------------------------------------------------------------------
__global__ __launch_bounds__(256) void gemm64_f32(
    const float* __restrict__ A, int lda,
    const float* __restrict__ W, int ldw,
    float* __restrict__ C, int ldc, size_t cstride)
{
  const int tid = threadIdx.x;
  const int tx = tid & 15, ty = tid >> 4;
  const int n0 = blockIdx.x * 64, m0 = blockIdx.y * 64;
  const int kb = blockIdx.z * 256;
  C += (size_t)blockIdx.z * cstride;

  __shared__ float As[64][36];
  __shared__ __align__(16) float Bs[32][64];

  float acc[4][4];
#pragma unroll
  for (int i = 0; i < 4; i++)
#pragma unroll
    for (int j = 0; j < 4; j++) acc[i][j] = 0.0f;

  for (int k0 = kb; k0 < kb + 256; k0 += 32) {
    {
      int c = tid * 2;
      int r = c >> 3, kq = c & 7;
      float4 v0 = *(const float4*)(A + (size_t)(m0 + r) * lda + k0 + kq * 4);
      float4 v1 = *(const float4*)(A + (size_t)(m0 + r) * lda + k0 + (kq + 1) * 4);
      As[r][kq * 4 + 0] = v0.x; As[r][kq * 4 + 1] = v0.y;
      As[r][kq * 4 + 2] = v0.z; As[r][kq * 4 + 3] = v0.w;
      As[r][kq * 4 + 4] = v1.x; As[r][kq * 4 + 5] = v1.y;
      As[r][kq * 4 + 6] = v1.z; As[r][kq * 4 + 7] = v1.w;
    }
    {
      int c = tid * 2;
      int kk = c >> 4, n4 = c & 15;
      *(float4*)(&Bs[kk][n4 * 4]) = *(const float4*)(W + (size_t)(k0 + kk) * ldw + n0 + n4 * 4);
      *(float4*)(&Bs[kk][n4 * 4 + 4]) = *(const float4*)(W + (size_t)(k0 + kk) * ldw + n0 + n4 * 4 + 4);
    }
    __syncthreads();
#pragma unroll
    for (int kk = 0; kk < 32; kk++) {
      float a[4], bfr[4];
#pragma unroll
      for (int i = 0; i < 4; i++) a[i] = As[ty * 4 + i][kk];
      *(float4*)&bfr[0] = *(const float4*)&Bs[kk][tx * 4];
#pragma unroll
      for (int i = 0; i < 4; i++)
#pragma unroll
        for (int j = 0; j < 4; j++)
          acc[i][j] = fmaf(a[i], bfr[j], acc[i][j]);
    }
    __syncthreads();
  }

#pragma unroll
  for (int i = 0; i < 4; i++) {
    float* cp = C + (size_t)(m0 + ty * 4 + i) * ldc + n0 + tx * 4;
    *(float4*)cp = make_float4(acc[i][0], acc[i][1], acc[i][2], acc[i][3]);
  }
}

// Reduce split-K partials + bias, scatter to sel rows.
__global__ __launch_bounds__(256) void epi_reduce(
    const float* __restrict__ partial,  // [8][512][256]
    const float* __restrict__ bu,
    float* __restrict__ out)
{
  const int bp = blockIdx.x, e = threadIdx.x;
  const int b = bp >> 7, p = bp & 127;
  const int selp = STRIDE * p + STRIDE - 1;
  float s = bu[e];
#pragma unroll
  for (int z = 0; z < 8; z++)
    s += partial[((size_t)z * (BB * TP) + bp) * EMB + e];
  out[((size_t)b * TT + selp) * EMB + e] = s;
}

// ---------------------------------------------------------------------------
__device__ __forceinline__ float softplus_f(float v) {
  return fmaxf(v, 0.0f) + log1pf(expf(-fabsf(v)));
}

__global__ __launch_bounds__(256) void params2_kernel(
    const float* __restrict__ hid0,
    const float* __restrict__ W1,
    const float* __restrict__ b1,
    const float* __restrict__ W2,
    const float* __restrict__ b2,
    const int* __restrict__ grand, const int* __restrict__ rrand,
    int* __restrict__ idx_out, float* __restrict__ w_out)
{
  const int bp = blockIdx.x;
  const int b = bp >> 7, p = bp & 127;
  const int selp = STRIDE * p + STRIDE - 1;
  const int tid = threadIdx.x;
  const float coordp = (float)p / (float)TP;

  __shared__ float shid[HID];
  __shared__ float spartial[256];
  __shared__ float spar[2 * KMIX];
  __shared__ float sm[KMIX], ss[KMIX];
  __shared__ int   sidx[VS];
  __shared__ float sidxf[VS];
  __shared__ int   svalid[VS];
  __shared__ float sprops[KMIX][VS];
  __shared__ float sden[KMIX];

#pragma unroll
  for (int q = 0; q < HID / 256; q++) {
    int j = q * 256 + tid;
    shid[j] = fmaxf(hid0[(size_t)bp * HID + j] + coordp * W1[(size_t)EMB * HID + j] + b1[j], 0.0f);
  }
  __syncthreads();

  {
    int o = tid & 15, g = tid >> 4;
    float pa = 0.0f;
    for (int jj = 0; jj < 64; jj++) {
      int j = g * 64 + jj;
      pa = fmaf(shid[j], W2[j * (2 * KMIX) + o], pa);
    }
    spartial[o * 16 + g] = pa;
  }
  __syncthreads();
  if (tid < 2 * KMIX) {
    float acc = 0.0f;
    for (int g = 0; g < 16; g++) acc += spartial[tid * 16 + g];
    spar[tid] = acc + b2[tid];
  }
  __syncthreads();

  if (tid < KMIX) {
    float m = (float)selp - 3.0f * softplus_f(spar[tid]);
    m = fminf(fmaxf(m, 0.0f), (float)(TT - 1));
    sm[tid] = m;
    ss[tid] = (softplus_f(spar[KMIX + tid] + 2.0f) + 0.05f) * (float)TT * 0.1f;
  }
  __syncthreads();

  if (tid < VS) {
    int kk = tid / 6, jj = tid % 6;
    float fl = floorf(sm[kk]);
    float v;
    if (jj == 0) v = fl;
    else if (jj == 1) v = fl + 1.0f;
    else if (jj < 4) v = (float)grand[(bp * KMIX + kk) * GADD + (jj - 2)];
    else {
      float lo = fminf(fmaxf(fl - (float)(REGION / 2), 0.0f), (float)(TT - REGION));
      v = lo + (float)rrand[(bp * KMIX + kk) * RADD + (jj - 4)];
    }
    v = fminf(fmaxf(v, 0.0f), (float)(TT - 1));
    int ii = (int)v;
    sidx[tid] = ii;
    sidxf[tid] = (float)ii;
  }
  __syncthreads();

  if (tid < VS) {
    int d = 0;
    for (int u = 0; u < tid; u++) d |= (sidx[u] == sidx[tid]);
    svalid[tid] = (!d) && (sidx[tid] <= selp);
  }
  __syncthreads();

  for (int l = tid; l < KMIX * VS; l += 256) {
    int kk = l / VS, v = l - kk * VS;
    float z = (sidxf[v] - sm[kk]) / ss[kk];
    sprops[kk][v] = svalid[v] ? expf(-0.5f * z * z) : 0.0f;
  }
  __syncthreads();
  if (tid < KMIX) {
    float den = 0.0f;
    for (int v = 0; v < VS; v++) den += sprops[tid][v];
    sden[tid] = den;
  }
  __syncthreads();

  if (tid < VS) {
    float w = 0.0f;
    for (int kk = 0; kk < KMIX; kk++) w += sprops[kk][tid] / sden[kk];
    w_out[(size_t)bp * VS + tid] = w;
    idx_out[(size_t)bp * VS + tid] = sidx[tid];
  }
}

// ---------------------------------------------------------------------------
__global__ void fill_out(const float* __restrict__ bu, float* __restrict__ out, int total) {
  int i = blockIdx.x * 256 + threadIdx.x;
  if (i < total) out[i] = bu[i & (EMB - 1)];
}

// ---------------------------------------------------------------------------
// Attention phase 1, one block per (p, head) of one batch.
// ---------------------------------------------------------------------------
__global__ __launch_bounds__(256) void attn2_kernel(
    const float* __restrict__ Qsel,  // [B*TP, NQ]
    const float* __restrict__ Kb,    // [T, NQ] this batch
    const float* __restrict__ Vb,    // [T, NQ]
    const int* __restrict__ idx_in,  // [B*TP, VS]
    const float* __restrict__ w_in,  // [B*TP, VS]
    float* __restrict__ outp_all,    // [B*TP, NQ]
    int b)
{
  const int p = blockIdx.x, h = blockIdx.y;
  const int bp = b * TP + p;
  const int tid = threadIdx.x;
  const int wave = tid >> 6, lane = tid & 63;

  __shared__ __align__(16) float q[EMB];
  __shared__ int   sidx[VS];
  __shared__ float sw[VS];
  __shared__ float sdot[VS];
  __shared__ float satt[VS];

  q[tid] = Qsel[(size_t)bp * NQ + h * 256 + tid];
  if (tid < VS) {
    sidx[tid] = idx_in[(size_t)bp * VS + tid];
    sw[tid]   = w_in[(size_t)bp * VS + tid];
  }
  __syncthreads();

  {
    float4 qq = *(const float4*)(q + lane * 4);
    for (int v = wave; v < VS; v += 4) {
      const float* kr = Kb + (size_t)sidx[v] * NQ + h * 256 + lane * 4;
      float4 kv = *(const float4*)kr;
      float par = qq.x * kv.x + qq.y * kv.y + qq.z * kv.z + qq.w * kv.w;
#pragma unroll
      for (int m = 32; m >= 1; m >>= 1) par += __shfl_xor(par, m, 64);
      if (lane == 0) sdot[v] = par;
    }
  }
  __syncthreads();

  if (tid < 64) {
    float logit = (lane < VS) ? sw[lane] * sdot[lane] : -1e30f;
    float mx = logit;
#pragma unroll
    for (int m = 32; m >= 1; m >>= 1) mx = fmaxf(mx, __shfl_xor(mx, m, 64));
    float e = (lane < VS) ? __expf(logit - mx) : 0.0f;
    float sum = e;
#pragma unroll
    for (int m = 32; m >= 1; m >>= 1) sum += __shfl_xor(sum, m, 64);
    if (lane < VS) satt[lane] = e / sum;
  }
  __syncthreads();

  {
    float a0 = 0.f, a1 = 0.f, a2 = 0.f, a3 = 0.f;
#pragma unroll 4
    for (int v = 0; v < VS; v += 4) {
      a0 = fmaf(satt[v + 0], Vb[(size_t)sidx[v + 0] * NQ + h * 256 + tid], a0);
      a1 = fmaf(satt[v + 1], Vb[(size_t)sidx[v + 1] * NQ + h * 256 + tid], a1);
      a2 = fmaf(satt[v + 2], Vb[(size_t)sidx[v + 2] * NQ + h * 256 + tid], a2);
      a3 = fmaf(satt[v + 3], Vb[(size_t)sidx[v + 3] * NQ + h * 256 + tid], a3);
    }
    outp_all[(size_t)bp * NQ + h * 256 + tid] = (a0 + a1) + (a2 + a3);
  }
}

// ---------------------------------------------------------------------------
extern "C" void kernel_launch(void* const* d_in, const int* in_sizes, int n_in,
                              void* d_out, int out_size, void* d_ws, size_t ws_size,
                              hipStream_t stream) {
  const float* x  = (const float*)d_in[0];
  const float* Wq = (const float*)d_in[1];
  const float* Wk = (const float*)d_in[2];
  const float* Wv = (const float*)d_in[3];
  const float* Wu = (const float*)d_in[4];
  const float* bu = (const float*)d_in[5];
  const float* W1 = (const float*)d_in[6];
  const float* b1 = (const float*)d_in[7];
  const float* W2 = (const float*)d_in[8];
  const float* b2 = (const float*)d_in[9];
  float* out = (float*)d_out;

  // ---- workspace layout ----
  char* ws = (char*)d_ws;
  size_t off = 0;
  auto alloc = [&](size_t bytes) { char* p = ws + off; off += (bytes + 255) & ~(size_t)255; return p; };
  float* Kb    = (float*)alloc((size_t)TT * NQ * 4);        // 32 MB
  float* Vb    = (float*)alloc((size_t)TT * NQ * 4);        // 32 MB
  float* Qsel  = (float*)alloc((size_t)BB * TP * NQ * 4);   // 4 MB
  float* outp  = (float*)alloc((size_t)BB * TP * NQ * 4);   // 4 MB
  float* part  = (float*)alloc((size_t)8 * BB * TP * EMB * 4); // 4 MB
  short* Xh    = (short*)alloc((size_t)BB * TT * EMB * 2);  // 8 MB
  short* Wqth  = (short*)alloc((size_t)NQ * EMB * 2);
  short* Wqtl  = (short*)alloc((size_t)NQ * EMB * 2);
  short* Wkth  = (short*)alloc((size_t)NQ * EMB * 2);
  short* Wktl  = (short*)alloc((size_t)NQ * EMB * 2);
  short* Wvth  = (short*)alloc((size_t)NQ * EMB * 2);
  short* Wvtl  = (short*)alloc((size_t)NQ * EMB * 2);
  float* xsel  = (float*)alloc((size_t)BB * TP * EMB * 4);
  short* xselh = (short*)alloc((size_t)BB * TP * EMB * 2);
  float* hid0  = (float*)alloc((size_t)BB * TP * HID * 4);  // 2 MB
  int*   idxb  = (int*)  alloc((size_t)BB * TP * VS * 4);
  float* wts   = (float*)alloc((size_t)BB * TP * VS * 4);
  int*   grand = (int*)  alloc((size_t)BB * TP * KMIX * GADD * 4);
  int*   rrand = (int*)  alloc((size_t)BB * TP * KMIX * RADD * 4);

  // 1. RNG + prepasses
  rand_kernel<<<dim3(32), dim3(256), 0, stream>>>(grand, rrand);
  prep_x_hi<<<dim3((BB * TT * EMB) / (256 * 8)), dim3(256), 0, stream>>>(x, Xh);
  prep_w_split<<<dim3(NQ / 32, EMB / 32, 3), dim3(256), 0, stream>>>(
      Wq, Wk, Wv, Wqth, Wqtl, Wkth, Wktl, Wvth, Wvtl);
  prep_sel<<<dim3(BB * TP), dim3(256), 0, stream>>>(x, xsel, xselh);

  // 2. MLP gemm (fp32, 64x64 tiles) + params finish
  gemm64_f32<<<dim3(HID / 64, (BB * TP) / 64, 1), dim3(256), 0, stream>>>(
      xsel, EMB, W1, HID, hid0, HID, 0);
  params2_kernel<<<dim3(BB * TP), dim3(256), 0, stream>>>(
      hid0, W1, b1, W2, b2, grand, rrand, idxb, wts);

  // 3. Q projection (2-term split MFMA); 1/16 folds both 1/e^0.25 factors
  gemm_split2<<<dim3(NQ / 128, (BB * TP) / 128, 1), dim3(256), 0, stream>>>(
      xselh, Wqth, Wqtl, Wqth, Wqtl, Qsel, Qsel, 0.0625f);

  // 4. background output rows = bu
  fill_out<<<dim3((BB * TT * EMB) / 256), dim3(256), 0, stream>>>(
      bu, out, BB * TT * EMB);

  // 5. per-batch K/V projection (MFMA) + attention phase 1
  for (int b = 0; b < BB; b++) {
    const short* xbh = Xh + (size_t)b * TT * EMB;
    gemm_split2<<<dim3(NQ / 128, TT / 128, 2), dim3(256), 0, stream>>>(
        xbh, Wkth, Wktl, Wvth, Wvtl, Kb, Vb, 1.0f);
    attn2_kernel<<<dim3(TP, HEADS), dim3(256), 0, stream>>>(
        Qsel, Kb, Vb, idxb, wts, outp, b);
  }

  // 6. epilogue: split-K GEMM (outp @ Wu) then reduce + bias + scatter
  gemm64_f32<<<dim3(EMB / 64, (BB * TP) / 64, NQ / 256), dim3(256), 0, stream>>>(
      outp, NQ, Wu, EMB, part, EMB, (size_t)BB * TP * EMB);
  epi_reduce<<<dim3(BB * TP), dim3(256), 0, stream>>>(part, bu, out);
}

// Round 6
// 132.295 us; speedup vs baseline: 6.6972x; 2.5732x over previous
//
#include <hip/hip_runtime.h>
#include <stdint.h>

// ---------------------------------------------------------------------------
// Problem constants (from reference)
// ---------------------------------------------------------------------------
#define EMB   256
#define HEADS 8
#define KMIX  8
#define GADD  2
#define RADD  2
#define REGION 64
#define STRIDE 32
#define BB    4
#define TT    4096
#define TP    128
#define VS    48
#define HID   1024
#define NQ    2048

#define RNG_PARTITIONABLE 1

// ---------------------------------------------------------------------------
// Threefry-2x32 (JAX exact)
// ---------------------------------------------------------------------------
__device__ __forceinline__ uint32_t rotl32(uint32_t x, int d) {
  return (x << d) | (x >> (32 - d));
}
__device__ __forceinline__ void tf2x32(uint32_t k0, uint32_t k1,
                                       uint32_t x0, uint32_t x1,
                                       uint32_t& o0, uint32_t& o1) {
  uint32_t ks2 = k0 ^ k1 ^ 0x1BD11BDAu;
  x0 += k0; x1 += k1;
#define TFR(r) { x0 += x1; x1 = rotl32(x1, r); x1 ^= x0; }
  TFR(13) TFR(15) TFR(26) TFR(6)
  x0 += k1; x1 += ks2 + 1u;
  TFR(17) TFR(29) TFR(16) TFR(24)
  x0 += ks2; x1 += k0 + 2u;
  TFR(13) TFR(15) TFR(26) TFR(6)
  x0 += k0; x1 += k1 + 3u;
  TFR(17) TFR(29) TFR(16) TFR(24)
  x0 += k1; x1 += ks2 + 4u;
  TFR(13) TFR(15) TFR(26) TFR(6)
  x0 += ks2; x1 += k0 + 5u;
#undef TFR
  o0 = x0; o1 = x1;
}

__global__ void rand_kernel(int* __restrict__ grand, int* __restrict__ rrand) {
  int i = blockIdx.x * blockDim.x + threadIdx.x;
#if RNG_PARTITIONABLE
  uint32_t kg0, kg1, kr0, kr1;
  tf2x32(0u, 42u, 0u, 0u, kg0, kg1);
  tf2x32(0u, 42u, 0u, 1u, kr0, kr1);
  uint32_t g2k0, g2k1, r2k0, r2k1;
  tf2x32(kg0, kg1, 0u, 1u, g2k0, g2k1);
  tf2x32(kr0, kr1, 0u, 1u, r2k0, r2k1);
  if (i < BB * TP * KMIX * GADD) {
    uint32_t o0, o1;
    tf2x32(g2k0, g2k1, 0u, (uint32_t)i, o0, o1);
    grand[i] = (int)((o0 ^ o1) & 4095u);
    tf2x32(r2k0, r2k1, 0u, (uint32_t)i, o0, o1);
    rrand[i] = (int)((o0 ^ o1) & 63u);
  }
#else
  uint32_t a0, a1, b0, b1;
  tf2x32(0u, 42u, 0u, 2u, a0, a1);
  tf2x32(0u, 42u, 1u, 3u, b0, b1);
  uint32_t kg0 = a0, kg1 = b0, kr0 = a1, kr1 = b1;
  uint32_t c0, c1, d0, d1;
  tf2x32(kg0, kg1, 0u, 2u, c0, c1);
  tf2x32(kg0, kg1, 1u, 3u, d0, d1);
  uint32_t g2k0 = c1, g2k1 = d1;
  tf2x32(kr0, kr1, 0u, 2u, c0, c1);
  tf2x32(kr0, kr1, 1u, 3u, d0, d1);
  uint32_t r2k0 = c1, r2k1 = d1;
  if (i < 4096) {
    uint32_t o0, o1;
    tf2x32(g2k0, g2k1, (uint32_t)i, (uint32_t)(i + 4096), o0, o1);
    grand[i]        = (int)(o0 & 4095u);
    grand[i + 4096] = (int)(o1 & 4095u);
    tf2x32(r2k0, r2k1, (uint32_t)i, (uint32_t)(i + 4096), o0, o1);
    rrand[i]        = (int)(o0 & 63u);
    rrand[i + 4096] = (int)(o1 & 63u);
  }
#endif
}

// ---------------------------------------------------------------------------
// Prepass: extract sel rows of x -> xsel (f32)
// ---------------------------------------------------------------------------
__global__ __launch_bounds__(256) void prep_sel(
    const float* __restrict__ x, float* __restrict__ xsel) {
  const int bp = blockIdx.x, b = bp >> 7, p = bp & 127;
  const int selp = STRIDE * p + STRIDE - 1;
  const int tid = threadIdx.x;
  xsel[(size_t)bp * EMB + tid] = x[((size_t)b * TT + selp) * EMB + tid];
}

// ---------------------------------------------------------------------------
// NT GEMM (batched over z): C[m][n] = scale * sum_k A[m][k] * B[n][k]
// 64x64 tile, BK=32. Used for M_h = Wq_h @ Wk_h^T (z = head).
// ---------------------------------------------------------------------------
__global__ __launch_bounds__(256) void gemm_nt64(
    const float* __restrict__ A, int lda, size_t Az,
    const float* __restrict__ B, int ldb, size_t Bz,
    float* __restrict__ C, int ldc, size_t Cz,
    int kLen, float scale)
{
  A += (size_t)blockIdx.z * Az;
  B += (size_t)blockIdx.z * Bz;
  C += (size_t)blockIdx.z * Cz;
  const int tid = threadIdx.x;
  const int tx = tid & 15, ty = tid >> 4;
  const int n0 = blockIdx.x * 64, m0 = blockIdx.y * 64;

  __shared__ float As[64][36];
  __shared__ float Bs[64][36];

  float acc[4][4];
#pragma unroll
  for (int i = 0; i < 4; i++)
#pragma unroll
    for (int j = 0; j < 4; j++) acc[i][j] = 0.0f;

  for (int k0 = 0; k0 < kLen; k0 += 32) {
    {
      int c = tid * 2;
      int r = c >> 3, kq = c & 7;
      float4 v0 = *(const float4*)(A + (size_t)(m0 + r) * lda + k0 + kq * 4);
      float4 v1 = *(const float4*)(A + (size_t)(m0 + r) * lda + k0 + (kq + 1) * 4);
      As[r][kq * 4 + 0] = v0.x; As[r][kq * 4 + 1] = v0.y;
      As[r][kq * 4 + 2] = v0.z; As[r][kq * 4 + 3] = v0.w;
      As[r][kq * 4 + 4] = v1.x; As[r][kq * 4 + 5] = v1.y;
      As[r][kq * 4 + 6] = v1.z; As[r][kq * 4 + 7] = v1.w;
      float4 w0 = *(const float4*)(B + (size_t)(n0 + r) * ldb + k0 + kq * 4);
      float4 w1 = *(const float4*)(B + (size_t)(n0 + r) * ldb + k0 + (kq + 1) * 4);
      Bs[r][kq * 4 + 0] = w0.x; Bs[r][kq * 4 + 1] = w0.y;
      Bs[r][kq * 4 + 2] = w0.z; Bs[r][kq * 4 + 3] = w0.w;
      Bs[r][kq * 4 + 4] = w1.x; Bs[r][kq * 4 + 5] = w1.y;
      Bs[r][kq * 4 + 6] = w1.z; Bs[r][kq * 4 + 7] = w1.w;
    }
    __syncthreads();
#pragma unroll
    for (int kk = 0; kk < 32; kk++) {
      float a[4], bfr[4];
#pragma unroll
      for (int i = 0; i < 4; i++) a[i] = As[ty * 4 + i][kk];
#pragma unroll
      for (int j = 0; j < 4; j++) bfr[j] = Bs[tx * 4 + j][kk];
#pragma unroll
      for (int i = 0; i < 4; i++)
#pragma unroll
        for (int j = 0; j < 4; j++)
          acc[i][j] = fmaf(a[i], bfr[j], acc[i][j]);
    }
    __syncthreads();
  }

#pragma unroll
  for (int i = 0; i < 4; i++) {
    float* cp = C + (size_t)(m0 + ty * 4 + i) * ldc + n0 + tx * 4;
    *(float4*)cp = make_float4(acc[i][0] * scale, acc[i][1] * scale,
                               acc[i][2] * scale, acc[i][3] * scale);
  }
}

// ---------------------------------------------------------------------------
// NN GEMM (batched over z): C[m][n] = sum_k A[m][k] * W[k][n]
// 64x64 tile, BK=32. z applies element offsets Az/Wz/Cz.
// ---------------------------------------------------------------------------
__global__ __launch_bounds__(256) void gemm64_nn(
    const float* __restrict__ A, int lda, size_t Az,
    const float* __restrict__ W, int ldw, size_t Wz,
    float* __restrict__ C, int ldc, size_t Cz,
    int kLen)
{
  A += (size_t)blockIdx.z * Az;
  W += (size_t)blockIdx.z * Wz;
  C += (size_t)blockIdx.z * Cz;
  const int tid = threadIdx.x;
  const int tx = tid & 15, ty = tid >> 4;
  const int n0 = blockIdx.x * 64, m0 = blockIdx.y * 64;

  __shared__ float As[64][36];
  __shared__ __align__(16) float Bs[32][64];

  float acc[4][4];
#pragma unroll
  for (int i = 0; i < 4; i++)
#pragma unroll
    for (int j = 0; j < 4; j++) acc[i][j] = 0.0f;

  for (int k0 = 0; k0 < kLen; k0 += 32) {
    {
      int c = tid * 2;
      int r = c >> 3, kq = c & 7;
      float4 v0 = *(const float4*)(A + (size_t)(m0 + r) * lda + k0 + kq * 4);
      float4 v1 = *(const float4*)(A + (size_t)(m0 + r) * lda + k0 + (kq + 1) * 4);
      As[r][kq * 4 + 0] = v0.x; As[r][kq * 4 + 1] = v0.y;
      As[r][kq * 4 + 2] = v0.z; As[r][kq * 4 + 3] = v0.w;
      As[r][kq * 4 + 4] = v1.x; As[r][kq * 4 + 5] = v1.y;
      As[r][kq * 4 + 6] = v1.z; As[r][kq * 4 + 7] = v1.w;
    }
    {
      int c = tid * 2;
      int kk = c >> 4, n4 = c & 15;
      *(float4*)(&Bs[kk][n4 * 4]) = *(const float4*)(W + (size_t)(k0 + kk) * ldw + n0 + n4 * 4);
      *(float4*)(&Bs[kk][n4 * 4 + 4]) = *(const float4*)(W + (size_t)(k0 + kk) * ldw + n0 + n4 * 4 + 4);
    }
    __syncthreads();
#pragma unroll
    for (int kk = 0; kk < 32; kk++) {
      float a[4], bfr[4];
#pragma unroll
      for (int i = 0; i < 4; i++) a[i] = As[ty * 4 + i][kk];
      *(float4*)&bfr[0] = *(const float4*)&Bs[kk][tx * 4];
#pragma unroll
      for (int i = 0; i < 4; i++)
#pragma unroll
        for (int j = 0; j < 4; j++)
          acc[i][j] = fmaf(a[i], bfr[j], acc[i][j]);
    }
    __syncthreads();
  }

#pragma unroll
  for (int i = 0; i < 4; i++) {
    float* cp = C + (size_t)(m0 + ty * 4 + i) * ldc + n0 + tx * 4;
    *(float4*)cp = make_float4(acc[i][0], acc[i][1], acc[i][2], acc[i][3]);
  }
}

// ---------------------------------------------------------------------------
// Split-K fp32 GEMM over K-chunks of 256 (epilogue). grid=(N/64,M/64,K/256).
// ---------------------------------------------------------------------------
__global__ __launch_bounds__(256) void gemm64_f32(
    const float* __restrict__ A, int lda,
    const float* __restrict__ W, int ldw,
    float* __restrict__ C, int ldc, size_t cstride)
{
  const int tid = threadIdx.x;
  const int tx = tid & 15, ty = tid >> 4;
  const int n0 = blockIdx.x * 64, m0 = blockIdx.y * 64;
  const int kb = blockIdx.z * 256;
  C += (size_t)blockIdx.z * cstride;

  __shared__ float As[64][36];
  __shared__ __align__(16) float Bs[32][64];

  float acc[4][4];
#pragma unroll
  for (int i = 0; i < 4; i++)
#pragma unroll
    for (int j = 0; j < 4; j++) acc[i][j] = 0.0f;

  for (int k0 = kb; k0 < kb + 256; k0 += 32) {
    {
      int c = tid * 2;
      int r = c >> 3, kq = c & 7;
      float4 v0 = *(const float4*)(A + (size_t)(m0 + r) * lda + k0 + kq * 4);
      float4 v1 = *(const float4*)(A + (size_t)(m0 + r) * lda + k0 + (kq + 1) * 4);
      As[r][kq * 4 + 0] = v0.x; As[r][kq * 4 + 1] = v0.y;
      As[r][kq * 4 + 2] = v0.z; As[r][kq * 4 + 3] = v0.w;
      As[r][kq * 4 + 4] = v1.x; As[r][kq * 4 + 5] = v1.y;
      As[r][kq * 4 + 6] = v1.z; As[r][kq * 4 + 7] = v1.w;
    }
    {
      int c = tid * 2;
      int kk = c >> 4, n4 = c & 15;
      *(float4*)(&Bs[kk][n4 * 4]) = *(const float4*)(W + (size_t)(k0 + kk) * ldw + n0 + n4 * 4);
      *(float4*)(&Bs[kk][n4 * 4 + 4]) = *(const float4*)(W + (size_t)(k0 + kk) * ldw + n0 + n4 * 4 + 4);
    }
    __syncthreads();
#pragma unroll
    for (int kk = 0; kk < 32; kk++) {
      float a[4], bfr[4];
#pragma unroll
      for (int i = 0; i < 4; i++) a[i] = As[ty * 4 + i][kk];
      *(float4*)&bfr[0] = *(const float4*)&Bs[kk][tx * 4];
#pragma unroll
      for (int i = 0; i < 4; i++)
#pragma unroll
        for (int j = 0; j < 4; j++)
          acc[i][j] = fmaf(a[i], bfr[j], acc[i][j]);
    }
    __syncthreads();
  }

#pragma unroll
  for (int i = 0; i < 4; i++) {
    float* cp = C + (size_t)(m0 + ty * 4 + i) * ldc + n0 + tx * 4;
    *(float4*)cp = make_float4(acc[i][0], acc[i][1], acc[i][2], acc[i][3]);
  }
}

// Reduce split-K partials + bias, scatter to sel rows.
__global__ __launch_bounds__(256) void epi_reduce(
    const float* __restrict__ partial,  // [8][512][256]
    const float* __restrict__ bu,
    float* __restrict__ out)
{
  const int bp = blockIdx.x, e = threadIdx.x;
  const int b = bp >> 7, p = bp & 127;
  const int selp = STRIDE * p + STRIDE - 1;
  float s = bu[e];
#pragma unroll
  for (int z = 0; z < 8; z++)
    s += partial[((size_t)z * (BB * TP) + bp) * EMB + e];
  out[((size_t)b * TT + selp) * EMB + e] = s;
}

// ---------------------------------------------------------------------------
__device__ __forceinline__ float softplus_f(float v) {
  return fmaxf(v, 0.0f) + log1pf(expf(-fabsf(v)));
}

__global__ __launch_bounds__(256) void params2_kernel(
    const float* __restrict__ hid0,
    const float* __restrict__ W1,
    const float* __restrict__ b1,
    const float* __restrict__ W2,
    const float* __restrict__ b2,
    const int* __restrict__ grand, const int* __restrict__ rrand,
    int* __restrict__ idx_out, float* __restrict__ w_out)
{
  const int bp = blockIdx.x;
  const int b = bp >> 7, p = bp & 127;
  const int selp = STRIDE * p + STRIDE - 1;
  const int tid = threadIdx.x;
  const float coordp = (float)p / (float)TP;

  __shared__ float shid[HID];
  __shared__ float spartial[256];
  __shared__ float spar[2 * KMIX];
  __shared__ float sm[KMIX], ss[KMIX];
  __shared__ int   sidx[VS];
  __shared__ float sidxf[VS];
  __shared__ int   svalid[VS];
  __shared__ float sprops[KMIX][VS];
  __shared__ float sden[KMIX];

#pragma unroll
  for (int q = 0; q < HID / 256; q++) {
    int j = q * 256 + tid;
    shid[j] = fmaxf(hid0[(size_t)bp * HID + j] + coordp * W1[(size_t)EMB * HID + j] + b1[j], 0.0f);
  }
  __syncthreads();

  {
    int o = tid & 15, g = tid >> 4;
    float pa = 0.0f;
    for (int jj = 0; jj < 64; jj++) {
      int j = g * 64 + jj;
      pa = fmaf(shid[j], W2[j * (2 * KMIX) + o], pa);
    }
    spartial[o * 16 + g] = pa;
  }
  __syncthreads();
  if (tid < 2 * KMIX) {
    float acc = 0.0f;
    for (int g = 0; g < 16; g++) acc += spartial[tid * 16 + g];
    spar[tid] = acc + b2[tid];
  }
  __syncthreads();

  if (tid < KMIX) {
    float m = (float)selp - 3.0f * softplus_f(spar[tid]);
    m = fminf(fmaxf(m, 0.0f), (float)(TT - 1));
    sm[tid] = m;
    ss[tid] = (softplus_f(spar[KMIX + tid] + 2.0f) + 0.05f) * (float)TT * 0.1f;
  }
  __syncthreads();

  if (tid < VS) {
    int kk = tid / 6, jj = tid % 6;
    float fl = floorf(sm[kk]);
    float v;
    if (jj == 0) v = fl;
    else if (jj == 1) v = fl + 1.0f;
    else if (jj < 4) v = (float)grand[(bp * KMIX + kk) * GADD + (jj - 2)];
    else {
      float lo = fminf(fmaxf(fl - (float)(REGION / 2), 0.0f), (float)(TT - REGION));
      v = lo + (float)rrand[(bp * KMIX + kk) * RADD + (jj - 4)];
    }
    v = fminf(fmaxf(v, 0.0f), (float)(TT - 1));
    int ii = (int)v;
    sidx[tid] = ii;
    sidxf[tid] = (float)ii;
  }
  __syncthreads();

  if (tid < VS) {
    int d = 0;
    for (int u = 0; u < tid; u++) d |= (sidx[u] == sidx[tid]);
    svalid[tid] = (!d) && (sidx[tid] <= selp);
  }
  __syncthreads();

  for (int l = tid; l < KMIX * VS; l += 256) {
    int kk = l / VS, v = l - kk * VS;
    float z = (sidxf[v] - sm[kk]) / ss[kk];
    sprops[kk][v] = svalid[v] ? expf(-0.5f * z * z) : 0.0f;
  }
  __syncthreads();
  if (tid < KMIX) {
    float den = 0.0f;
    for (int v = 0; v < VS; v++) den += sprops[tid][v];
    sden[tid] = den;
  }
  __syncthreads();

  if (tid < VS) {
    float w = 0.0f;
    for (int kk = 0; kk < KMIX; kk++) w += sprops[kk][tid] / sden[kk];
    w_out[(size_t)bp * VS + tid] = w;
    idx_out[(size_t)bp * VS + tid] = sidx[tid];
  }
}

// ---------------------------------------------------------------------------
__global__ void fill_out(const float* __restrict__ bu, float* __restrict__ out, int total) {
  int i = blockIdx.x * 256 + threadIdx.x;
  if (i < total) out[i] = bu[i & (EMB - 1)];
}

// ---------------------------------------------------------------------------
// Fused attention via re-association. One block per bp:
//   gather xg[v] = x[b, idx_v, :]           (48 x 256 f32 in LDS)
//   dots[h][v]  = qk[bp,h] . xg[v]          (qk = xsel @ Wq_h Wk_h^T / 16)
//   att         = softmax(w * dots)
//   z[bp,h]     = sum_v att[h][v] * xg[v]   (-> z @ Wv_h later)
// ---------------------------------------------------------------------------
__global__ __launch_bounds__(256) void attn3_kernel(
    const float* __restrict__ x,     // [B,T,EMB]
    const float* __restrict__ qk,    // [B*TP, NQ]
    const int* __restrict__ idx_in,  // [B*TP, VS]
    const float* __restrict__ w_in,  // [B*TP, VS]
    float* __restrict__ z)           // [B*TP, NQ]
{
  const int bp = blockIdx.x, b = bp >> 7;
  const int tid = threadIdx.x;

  __shared__ float xg[VS][260];
  __shared__ float qks[HEADS][EMB];
  __shared__ float att[HEADS][VS];
  __shared__ float sdot[HEADS][VS];
  __shared__ int   sidx[VS];
  __shared__ float sw[VS];

  if (tid < VS) {
    sidx[tid] = idx_in[(size_t)bp * VS + tid];
    sw[tid]   = w_in[(size_t)bp * VS + tid];
  }
#pragma unroll
  for (int r = 0; r < HEADS; r++)
    qks[r][tid] = qk[(size_t)bp * NQ + r * 256 + tid];
  __syncthreads();

  // gather 48 rows of x (4 rows per iteration, 64 lanes x float4)
  {
    const int vq = tid >> 6, lane = tid & 63;
#pragma unroll
    for (int it = 0; it < 12; it++) {
      int v = it * 4 + vq;
      float4 f = *(const float4*)(x + ((size_t)b * TT + sidx[v]) * EMB + lane * 4);
      xg[v][lane * 4 + 0] = f.x; xg[v][lane * 4 + 1] = f.y;
      xg[v][lane * 4 + 2] = f.z; xg[v][lane * 4 + 3] = f.w;
    }
  }
  __syncthreads();

  // dots: thread (h = tid>>5, l32 = tid&31) does v = l32 and v = l32+32 (if <48)
  {
    const int h = tid >> 5, l32 = tid & 31;
#pragma unroll
    for (int rep = 0; rep < 2; rep++) {
      int v = l32 + rep * 32;
      if (v < VS) {
        float acc = 0.0f;
        for (int j = 0; j < EMB; j++)
          acc = fmaf(qks[h][j], xg[v][j], acc);
        sdot[h][v] = acc;
      }
    }
  }
  __syncthreads();

  // softmax per head (8 threads)
  if (tid < HEADS) {
    float mx = -1e30f;
    for (int v = 0; v < VS; v++) mx = fmaxf(mx, sw[v] * sdot[tid][v]);
    float sum = 0.0f;
    for (int v = 0; v < VS; v++) {
      float e = expf(sw[v] * sdot[tid][v] - mx);
      att[tid][v] = e;
      sum += e;
    }
    float inv = 1.0f / sum;
    for (int v = 0; v < VS; v++) att[tid][v] *= inv;
  }
  __syncthreads();

  // z: thread = dim e, all 8 heads
  {
    float acc[HEADS];
#pragma unroll
    for (int h = 0; h < HEADS; h++) acc[h] = 0.0f;
    for (int v = 0; v < VS; v++) {
      float xv = xg[v][tid];
#pragma unroll
      for (int h = 0; h < HEADS; h++)
        acc[h] = fmaf(att[h][v], xv, acc[h]);
    }
#pragma unroll
    for (int h = 0; h < HEADS; h++)
      z[(size_t)bp * NQ + h * 256 + tid] = acc[h];
  }
}

// ---------------------------------------------------------------------------
extern "C" void kernel_launch(void* const* d_in, const int* in_sizes, int n_in,
                              void* d_out, int out_size, void* d_ws, size_t ws_size,
                              hipStream_t stream) {
  const float* x  = (const float*)d_in[0];
  const float* Wq = (const float*)d_in[1];
  const float* Wk = (const float*)d_in[2];
  const float* Wv = (const float*)d_in[3];
  const float* Wu = (const float*)d_in[4];
  const float* bu = (const float*)d_in[5];
  const float* W1 = (const float*)d_in[6];
  const float* b1 = (const float*)d_in[7];
  const float* W2 = (const float*)d_in[8];
  const float* b2 = (const float*)d_in[9];
  float* out = (float*)d_out;

  // ---- workspace layout (~21 MB) ----
  char* ws = (char*)d_ws;
  size_t off = 0;
  auto alloc = [&](size_t bytes) { char* p = ws + off; off += (bytes + 255) & ~(size_t)255; return p; };
  float* xsel  = (float*)alloc((size_t)BB * TP * EMB * 4);      // 0.5 MB
  float* hid0  = (float*)alloc((size_t)BB * TP * HID * 4);      // 2 MB
  float* M8    = (float*)alloc((size_t)HEADS * EMB * EMB * 4);  // 2 MB
  float* qk    = (float*)alloc((size_t)BB * TP * NQ * 4);       // 4 MB
  float* zbuf  = (float*)alloc((size_t)BB * TP * NQ * 4);       // 4 MB
  float* outp  = (float*)alloc((size_t)BB * TP * NQ * 4);       // 4 MB
  float* part  = (float*)alloc((size_t)8 * BB * TP * EMB * 4);  // 4 MB
  int*   idxb  = (int*)  alloc((size_t)BB * TP * VS * 4);
  float* wts   = (float*)alloc((size_t)BB * TP * VS * 4);
  int*   grand = (int*)  alloc((size_t)BB * TP * KMIX * GADD * 4);
  int*   rrand = (int*)  alloc((size_t)BB * TP * KMIX * RADD * 4);

  // 1. RNG + sel-row extraction
  rand_kernel<<<dim3(32), dim3(256), 0, stream>>>(grand, rrand);
  prep_sel<<<dim3(BB * TP), dim3(256), 0, stream>>>(x, xsel);

  // 2. M_h = (Wq_h @ Wk_h^T) / 16   [8][256][256]   (z = head)
  gemm_nt64<<<dim3(EMB / 64, EMB / 64, HEADS), dim3(256), 0, stream>>>(
      Wq, NQ, 256, Wk, NQ, 256, M8, EMB, (size_t)EMB * EMB, EMB, 0.0625f);

  // 3. MLP hidden + params (indices/weights)
  gemm64_nn<<<dim3(HID / 64, (BB * TP) / 64, 1), dim3(256), 0, stream>>>(
      xsel, EMB, 0, W1, HID, 0, hid0, HID, 0, EMB);
  params2_kernel<<<dim3(BB * TP), dim3(256), 0, stream>>>(
      hid0, W1, b1, W2, b2, grand, rrand, idxb, wts);

  // 4. qk[bp, h] = xsel @ M_h   (z = head)
  gemm64_nn<<<dim3(EMB / 64, (BB * TP) / 64, HEADS), dim3(256), 0, stream>>>(
      xsel, EMB, 0, M8, EMB, (size_t)EMB * EMB, qk, NQ, 256, EMB);

  // 5. fused attention (gather + dots + softmax + z), all batches
  attn3_kernel<<<dim3(BB * TP), dim3(256), 0, stream>>>(
      x, qk, idxb, wts, zbuf);

  // 6. outp[bp, h] = z_h @ Wv_h   (z = head)
  gemm64_nn<<<dim3(EMB / 64, (BB * TP) / 64, HEADS), dim3(256), 0, stream>>>(
      zbuf, NQ, 256, Wv, NQ, 256, outp, NQ, 256, EMB);

  // 7. background output rows = bu
  fill_out<<<dim3((BB * TT * EMB) / 256), dim3(256), 0, stream>>>(
      bu, out, BB * TT * EMB);

  // 8. epilogue: split-K GEMM (outp @ Wu) then reduce + bias + scatter
  gemm64_f32<<<dim3(EMB / 64, (BB * TP) / 64, NQ / 256), dim3(256), 0, stream>>>(
      outp, NQ, Wu, EMB, part, EMB, (size_t)BB * TP * EMB);
  epi_reduce<<<dim3(BB * TP), dim3(256), 0, stream>>>(part, bu, out);
}

// Round 7
// 101.303 us; speedup vs baseline: 8.7461x; 1.3059x over previous
//
#include <hip/hip_runtime.h>
#include <stdint.h>

// ---------------------------------------------------------------------------
// Problem constants (from reference)
// ---------------------------------------------------------------------------
#define EMB   256
#define HEADS 8
#define KMIX  8
#define GADD  2
#define RADD  2
#define REGION 64
#define STRIDE 32
#define BB    4
#define TT    4096
#define TP    128
#define VS    48
#define HID   1024
#define NQ    2048

#define RNG_PARTITIONABLE 1

// ---------------------------------------------------------------------------
// Threefry-2x32 (JAX exact)
// ---------------------------------------------------------------------------
__device__ __forceinline__ uint32_t rotl32(uint32_t x, int d) {
  return (x << d) | (x >> (32 - d));
}
__device__ __forceinline__ void tf2x32(uint32_t k0, uint32_t k1,
                                       uint32_t x0, uint32_t x1,
                                       uint32_t& o0, uint32_t& o1) {
  uint32_t ks2 = k0 ^ k1 ^ 0x1BD11BDAu;
  x0 += k0; x1 += k1;
#define TFR(r) { x0 += x1; x1 = rotl32(x1, r); x1 ^= x0; }
  TFR(13) TFR(15) TFR(26) TFR(6)
  x0 += k1; x1 += ks2 + 1u;
  TFR(17) TFR(29) TFR(16) TFR(24)
  x0 += ks2; x1 += k0 + 2u;
  TFR(13) TFR(15) TFR(26) TFR(6)
  x0 += k0; x1 += k1 + 3u;
  TFR(17) TFR(29) TFR(16) TFR(24)
  x0 += k1; x1 += ks2 + 4u;
  TFR(13) TFR(15) TFR(26) TFR(6)
  x0 += ks2; x1 += k0 + 5u;
#undef TFR
  o0 = x0; o1 = x1;
}

// ---------------------------------------------------------------------------
// Fused init: blocks [0,512) extract sel rows; blocks [512,544) do RNG.
// ---------------------------------------------------------------------------
__global__ __launch_bounds__(256) void init_kernel(
    const float* __restrict__ x, float* __restrict__ xsel,
    int* __restrict__ grand, int* __restrict__ rrand)
{
  const int blk = blockIdx.x, tid = threadIdx.x;
  if (blk < BB * TP) {
    const int b = blk >> 7, p = blk & 127;
    const int selp = STRIDE * p + STRIDE - 1;
    xsel[(size_t)blk * EMB + tid] = x[((size_t)b * TT + selp) * EMB + tid];
    return;
  }
  int i = (blk - BB * TP) * 256 + tid;
#if RNG_PARTITIONABLE
  uint32_t kg0, kg1, kr0, kr1;
  tf2x32(0u, 42u, 0u, 0u, kg0, kg1);
  tf2x32(0u, 42u, 0u, 1u, kr0, kr1);
  uint32_t g2k0, g2k1, r2k0, r2k1;
  tf2x32(kg0, kg1, 0u, 1u, g2k0, g2k1);
  tf2x32(kr0, kr1, 0u, 1u, r2k0, r2k1);
  if (i < BB * TP * KMIX * GADD) {
    uint32_t o0, o1;
    tf2x32(g2k0, g2k1, 0u, (uint32_t)i, o0, o1);
    grand[i] = (int)((o0 ^ o1) & 4095u);
    tf2x32(r2k0, r2k1, 0u, (uint32_t)i, o0, o1);
    rrand[i] = (int)((o0 ^ o1) & 63u);
  }
#else
  uint32_t a0, a1, b0, b1;
  tf2x32(0u, 42u, 0u, 2u, a0, a1);
  tf2x32(0u, 42u, 1u, 3u, b0, b1);
  uint32_t kg0 = a0, kg1 = b0, kr0 = a1, kr1 = b1;
  uint32_t c0, c1, d0, d1;
  tf2x32(kg0, kg1, 0u, 2u, c0, c1);
  tf2x32(kg0, kg1, 1u, 3u, d0, d1);
  uint32_t g2k0 = c1, g2k1 = d1;
  tf2x32(kr0, kr1, 0u, 2u, c0, c1);
  tf2x32(kr0, kr1, 1u, 3u, d0, d1);
  uint32_t r2k0 = c1, r2k1 = d1;
  if (i < 4096) {
    uint32_t o0, o1;
    tf2x32(g2k0, g2k1, (uint32_t)i, (uint32_t)(i + 4096), o0, o1);
    grand[i]        = (int)(o0 & 4095u);
    grand[i + 4096] = (int)(o1 & 4095u);
    tf2x32(r2k0, r2k1, (uint32_t)i, (uint32_t)(i + 4096), o0, o1);
    rrand[i]        = (int)(o0 & 63u);
    rrand[i + 4096] = (int)(o1 & 63u);
  }
#endif
}

// ---------------------------------------------------------------------------
// NN GEMM (batched over z): C[m][n] = sum_k A[m][k] * W[k][n]
// Tile M=32, N=64, BK=32; 256 threads; 2x4 per thread. 2 blocks/CU target.
// ---------------------------------------------------------------------------
__global__ __launch_bounds__(256) void gemm_nn(
    const float* __restrict__ A, int lda, size_t Az,
    const float* __restrict__ W, int ldw, size_t Wz,
    float* __restrict__ C, int ldc, size_t Cz,
    int kLen)
{
  A += (size_t)blockIdx.z * Az;
  W += (size_t)blockIdx.z * Wz;
  C += (size_t)blockIdx.z * Cz;
  const int tid = threadIdx.x;
  const int tx = tid & 15, ty = tid >> 4;
  const int n0 = blockIdx.x * 64, m0 = blockIdx.y * 32;

  __shared__ float As[32][33];
  __shared__ __align__(16) float Bs[32][64];

  float acc[2][4];
#pragma unroll
  for (int i = 0; i < 2; i++)
#pragma unroll
    for (int j = 0; j < 4; j++) acc[i][j] = 0.0f;

  for (int k0 = 0; k0 < kLen; k0 += 32) {
    {
      // A tile: 32x32 = 256 float4 chunks, 1 per thread
      int r = tid >> 3, kq = tid & 7;
      float4 v = *(const float4*)(A + (size_t)(m0 + r) * lda + k0 + kq * 4);
      As[r][kq * 4 + 0] = v.x; As[r][kq * 4 + 1] = v.y;
      As[r][kq * 4 + 2] = v.z; As[r][kq * 4 + 3] = v.w;
    }
    {
      // B tile: 32x64 = 512 float4 chunks, 2 per thread
#pragma unroll
      for (int rr = 0; rr < 2; rr++) {
        int c = tid * 2 + rr;
        int kk = c >> 4, n4 = c & 15;
        *(float4*)(&Bs[kk][n4 * 4]) =
            *(const float4*)(W + (size_t)(k0 + kk) * ldw + n0 + n4 * 4);
      }
    }
    __syncthreads();
#pragma unroll
    for (int kk = 0; kk < 32; kk++) {
      float a0 = As[ty * 2 + 0][kk];
      float a1 = As[ty * 2 + 1][kk];
      float4 b4 = *(const float4*)&Bs[kk][tx * 4];
      acc[0][0] = fmaf(a0, b4.x, acc[0][0]);
      acc[0][1] = fmaf(a0, b4.y, acc[0][1]);
      acc[0][2] = fmaf(a0, b4.z, acc[0][2]);
      acc[0][3] = fmaf(a0, b4.w, acc[0][3]);
      acc[1][0] = fmaf(a1, b4.x, acc[1][0]);
      acc[1][1] = fmaf(a1, b4.y, acc[1][1]);
      acc[1][2] = fmaf(a1, b4.z, acc[1][2]);
      acc[1][3] = fmaf(a1, b4.w, acc[1][3]);
    }
    __syncthreads();
  }

#pragma unroll
  for (int i = 0; i < 2; i++) {
    float* cp = C + (size_t)(m0 + ty * 2 + i) * ldc + n0 + tx * 4;
    *(float4*)cp = make_float4(acc[i][0], acc[i][1], acc[i][2], acc[i][3]);
  }
}

// ---------------------------------------------------------------------------
// NT GEMM (batched over z): C[m][n] = scale * sum_k A[m][k] * B[n][k]
// Tile M=32, N=64, BK=32; 256 threads; 2x4 per thread.
// ---------------------------------------------------------------------------
__global__ __launch_bounds__(256) void gemm_nt(
    const float* __restrict__ A, int lda, size_t Az,
    const float* __restrict__ B, int ldb, size_t Bz,
    float* __restrict__ C, int ldc, size_t Cz,
    int kLen, float scale)
{
  A += (size_t)blockIdx.z * Az;
  B += (size_t)blockIdx.z * Bz;
  C += (size_t)blockIdx.z * Cz;
  const int tid = threadIdx.x;
  const int tx = tid & 15, ty = tid >> 4;
  const int n0 = blockIdx.x * 64, m0 = blockIdx.y * 32;

  __shared__ float As[32][33];
  __shared__ float Bs[64][33];

  float acc[2][4];
#pragma unroll
  for (int i = 0; i < 2; i++)
#pragma unroll
    for (int j = 0; j < 4; j++) acc[i][j] = 0.0f;

  for (int k0 = 0; k0 < kLen; k0 += 32) {
    {
      int r = tid >> 3, kq = tid & 7;
      float4 v = *(const float4*)(A + (size_t)(m0 + r) * lda + k0 + kq * 4);
      As[r][kq * 4 + 0] = v.x; As[r][kq * 4 + 1] = v.y;
      As[r][kq * 4 + 2] = v.z; As[r][kq * 4 + 3] = v.w;
    }
    {
#pragma unroll
      for (int rr = 0; rr < 2; rr++) {
        int c = tid * 2 + rr;
        int r = c >> 3, kq = c & 7;
        float4 v = *(const float4*)(B + (size_t)(n0 + r) * ldb + k0 + kq * 4);
        Bs[r][kq * 4 + 0] = v.x; Bs[r][kq * 4 + 1] = v.y;
        Bs[r][kq * 4 + 2] = v.z; Bs[r][kq * 4 + 3] = v.w;
      }
    }
    __syncthreads();
#pragma unroll
    for (int kk = 0; kk < 32; kk++) {
      float a0 = As[ty * 2 + 0][kk];
      float a1 = As[ty * 2 + 1][kk];
      float b0 = Bs[tx * 4 + 0][kk];
      float b1 = Bs[tx * 4 + 1][kk];
      float b2 = Bs[tx * 4 + 2][kk];
      float b3 = Bs[tx * 4 + 3][kk];
      acc[0][0] = fmaf(a0, b0, acc[0][0]);
      acc[0][1] = fmaf(a0, b1, acc[0][1]);
      acc[0][2] = fmaf(a0, b2, acc[0][2]);
      acc[0][3] = fmaf(a0, b3, acc[0][3]);
      acc[1][0] = fmaf(a1, b0, acc[1][0]);
      acc[1][1] = fmaf(a1, b1, acc[1][1]);
      acc[1][2] = fmaf(a1, b2, acc[1][2]);
      acc[1][3] = fmaf(a1, b3, acc[1][3]);
    }
    __syncthreads();
  }

#pragma unroll
  for (int i = 0; i < 2; i++) {
    float* cp = C + (size_t)(m0 + ty * 2 + i) * ldc + n0 + tx * 4;
    *(float4*)cp = make_float4(acc[i][0] * scale, acc[i][1] * scale,
                               acc[i][2] * scale, acc[i][3] * scale);
  }
}

// ---------------------------------------------------------------------------
__device__ __forceinline__ float softplus_f(float v) {
  return fmaxf(v, 0.0f) + log1pf(expf(-fabsf(v)));
}

__global__ __launch_bounds__(256) void params2_kernel(
    const float* __restrict__ hid0,
    const float* __restrict__ W1,
    const float* __restrict__ b1,
    const float* __restrict__ W2,
    const float* __restrict__ b2,
    const int* __restrict__ grand, const int* __restrict__ rrand,
    int* __restrict__ idx_out, float* __restrict__ w_out)
{
  const int bp = blockIdx.x;
  const int b = bp >> 7, p = bp & 127;
  const int selp = STRIDE * p + STRIDE - 1;
  const int tid = threadIdx.x;
  const float coordp = (float)p / (float)TP;

  __shared__ float shid[HID];
  __shared__ float spartial[256];
  __shared__ float spar[2 * KMIX];
  __shared__ float sm[KMIX], ss[KMIX];
  __shared__ int   sidx[VS];
  __shared__ float sidxf[VS];
  __shared__ int   svalid[VS];
  __shared__ float sprops[KMIX][VS];
  __shared__ float sden[KMIX];

#pragma unroll
  for (int q = 0; q < HID / 256; q++) {
    int j = q * 256 + tid;
    shid[j] = fmaxf(hid0[(size_t)bp * HID + j] + coordp * W1[(size_t)EMB * HID + j] + b1[j], 0.0f);
  }
  __syncthreads();

  {
    int o = tid & 15, g = tid >> 4;
    float pa = 0.0f;
    for (int jj = 0; jj < 64; jj++) {
      int j = g * 64 + jj;
      pa = fmaf(shid[j], W2[j * (2 * KMIX) + o], pa);
    }
    spartial[o * 16 + g] = pa;
  }
  __syncthreads();
  if (tid < 2 * KMIX) {
    float acc = 0.0f;
    for (int g = 0; g < 16; g++) acc += spartial[tid * 16 + g];
    spar[tid] = acc + b2[tid];
  }
  __syncthreads();

  if (tid < KMIX) {
    float m = (float)selp - 3.0f * softplus_f(spar[tid]);
    m = fminf(fmaxf(m, 0.0f), (float)(TT - 1));
    sm[tid] = m;
    ss[tid] = (softplus_f(spar[KMIX + tid] + 2.0f) + 0.05f) * (float)TT * 0.1f;
  }
  __syncthreads();

  if (tid < VS) {
    int kk = tid / 6, jj = tid % 6;
    float fl = floorf(sm[kk]);
    float v;
    if (jj == 0) v = fl;
    else if (jj == 1) v = fl + 1.0f;
    else if (jj < 4) v = (float)grand[(bp * KMIX + kk) * GADD + (jj - 2)];
    else {
      float lo = fminf(fmaxf(fl - (float)(REGION / 2), 0.0f), (float)(TT - REGION));
      v = lo + (float)rrand[(bp * KMIX + kk) * RADD + (jj - 4)];
    }
    v = fminf(fmaxf(v, 0.0f), (float)(TT - 1));
    int ii = (int)v;
    sidx[tid] = ii;
    sidxf[tid] = (float)ii;
  }
  __syncthreads();

  if (tid < VS) {
    int d = 0;
    for (int u = 0; u < tid; u++) d |= (sidx[u] == sidx[tid]);
    svalid[tid] = (!d) && (sidx[tid] <= selp);
  }
  __syncthreads();

  for (int l = tid; l < KMIX * VS; l += 256) {
    int kk = l / VS, v = l - kk * VS;
    float z = (sidxf[v] - sm[kk]) / ss[kk];
    sprops[kk][v] = svalid[v] ? expf(-0.5f * z * z) : 0.0f;
  }
  __syncthreads();
  if (tid < KMIX) {
    float den = 0.0f;
    for (int v = 0; v < VS; v++) den += sprops[tid][v];
    sden[tid] = den;
  }
  __syncthreads();

  if (tid < VS) {
    float w = 0.0f;
    for (int kk = 0; kk < KMIX; kk++) w += sprops[kk][tid] / sden[kk];
    w_out[(size_t)bp * VS + tid] = w;
    idx_out[(size_t)bp * VS + tid] = sidx[tid];
  }
}

// ---------------------------------------------------------------------------
// Fused attention via re-association. One block per bp.
// ---------------------------------------------------------------------------
__global__ __launch_bounds__(256) void attn3_kernel(
    const float* __restrict__ x,     // [B,T,EMB]
    const float* __restrict__ qk,    // [B*TP, NQ]
    const int* __restrict__ idx_in,  // [B*TP, VS]
    const float* __restrict__ w_in,  // [B*TP, VS]
    float* __restrict__ z)           // [B*TP, NQ]
{
  const int bp = blockIdx.x, b = bp >> 7;
  const int tid = threadIdx.x;

  __shared__ float xg[VS][260];
  __shared__ __align__(16) float qks[HEADS][EMB];
  __shared__ float att[HEADS][VS];
  __shared__ float sdot[HEADS][VS];
  __shared__ int   sidx[VS];
  __shared__ float sw[VS];

  if (tid < VS) {
    sidx[tid] = idx_in[(size_t)bp * VS + tid];
    sw[tid]   = w_in[(size_t)bp * VS + tid];
  }
#pragma unroll
  for (int r = 0; r < HEADS; r++)
    qks[r][tid] = qk[(size_t)bp * NQ + r * 256 + tid];
  __syncthreads();

  // gather 48 rows of x (4 rows per iteration, 64 lanes x float4)
  {
    const int vq = tid >> 6, lane = tid & 63;
#pragma unroll
    for (int it = 0; it < 12; it++) {
      int v = it * 4 + vq;
      float4 f = *(const float4*)(x + ((size_t)b * TT + sidx[v]) * EMB + lane * 4);
      xg[v][lane * 4 + 0] = f.x; xg[v][lane * 4 + 1] = f.y;
      xg[v][lane * 4 + 2] = f.z; xg[v][lane * 4 + 3] = f.w;
    }
  }
  __syncthreads();

  // dots: thread (h = tid>>5, l32 = tid&31) does v = l32 and v = l32+32
  {
    const int h = tid >> 5, l32 = tid & 31;
#pragma unroll
    for (int rep = 0; rep < 2; rep++) {
      int v = l32 + rep * 32;
      if (v < VS) {
        float a0 = 0.f, a1 = 0.f, a2 = 0.f, a3 = 0.f;
        for (int j = 0; j < EMB; j += 4) {
          float4 qv = *(const float4*)&qks[h][j];
          float4 xv = *(const float4*)&xg[v][j];
          a0 = fmaf(qv.x, xv.x, a0);
          a1 = fmaf(qv.y, xv.y, a1);
          a2 = fmaf(qv.z, xv.z, a2);
          a3 = fmaf(qv.w, xv.w, a3);
        }
        sdot[h][v] = (a0 + a1) + (a2 + a3);
      }
    }
  }
  __syncthreads();

  // softmax per head (8 threads)
  if (tid < HEADS) {
    float mx = -1e30f;
    for (int v = 0; v < VS; v++) mx = fmaxf(mx, sw[v] * sdot[tid][v]);
    float sum = 0.0f;
    for (int v = 0; v < VS; v++) {
      float e = expf(sw[v] * sdot[tid][v] - mx);
      att[tid][v] = e;
      sum += e;
    }
    float inv = 1.0f / sum;
    for (int v = 0; v < VS; v++) att[tid][v] *= inv;
  }
  __syncthreads();

  // z: thread = dim e, all 8 heads
  {
    float acc[HEADS];
#pragma unroll
    for (int h = 0; h < HEADS; h++) acc[h] = 0.0f;
    for (int v = 0; v < VS; v++) {
      float xv = xg[v][tid];
#pragma unroll
      for (int h = 0; h < HEADS; h++)
        acc[h] = fmaf(att[h][v], xv, acc[h]);
    }
#pragma unroll
    for (int h = 0; h < HEADS; h++)
      z[(size_t)bp * NQ + h * 256 + tid] = acc[h];
  }
}

// ---------------------------------------------------------------------------
// Final output pass: out[b,t,:] = bu + (t sel ? sum_h part[h][bp] : 0)
// One float4 per thread; grid covers B*T*EMB/4.
// ---------------------------------------------------------------------------
__global__ __launch_bounds__(256) void final_out(
    const float* __restrict__ part,  // [8][512][256]
    const float* __restrict__ bu,
    float* __restrict__ out)
{
  int i4 = blockIdx.x * 256 + threadIdx.x;     // float4 index
  const int e4 = i4 & 63;
  const int row = i4 >> 6;                      // b*TT + t
  const int t = row & (TT - 1), b = row >> 12;
  float4 r = ((const float4*)bu)[e4];
  if ((t & 31) == 31) {
    const int bp = b * TP + (t >> 5);
#pragma unroll
    for (int h = 0; h < HEADS; h++) {
      float4 pv = *(const float4*)&part[((size_t)h * (BB * TP) + bp) * EMB + e4 * 4];
      r.x += pv.x; r.y += pv.y; r.z += pv.z; r.w += pv.w;
    }
  }
  ((float4*)out)[i4] = r;
}

// ---------------------------------------------------------------------------
extern "C" void kernel_launch(void* const* d_in, const int* in_sizes, int n_in,
                              void* d_out, int out_size, void* d_ws, size_t ws_size,
                              hipStream_t stream) {
  const float* x  = (const float*)d_in[0];
  const float* Wq = (const float*)d_in[1];
  const float* Wk = (const float*)d_in[2];
  const float* Wv = (const float*)d_in[3];
  const float* Wu = (const float*)d_in[4];
  const float* bu = (const float*)d_in[5];
  const float* W1 = (const float*)d_in[6];
  const float* b1 = (const float*)d_in[7];
  const float* W2 = (const float*)d_in[8];
  const float* b2 = (const float*)d_in[9];
  float* out = (float*)d_out;

  // ---- workspace layout (~19 MB) ----
  char* ws = (char*)d_ws;
  size_t off = 0;
  auto alloc = [&](size_t bytes) { char* p = ws + off; off += (bytes + 255) & ~(size_t)255; return p; };
  float* xsel  = (float*)alloc((size_t)BB * TP * EMB * 4);      // 0.5 MB
  float* hid0  = (float*)alloc((size_t)BB * TP * HID * 4);      // 2 MB
  float* M8    = (float*)alloc((size_t)HEADS * EMB * EMB * 4);  // 2 MB
  float* PV    = (float*)alloc((size_t)HEADS * EMB * EMB * 4);  // 2 MB
  float* qk    = (float*)alloc((size_t)BB * TP * NQ * 4);       // 4 MB
  float* zbuf  = (float*)alloc((size_t)BB * TP * NQ * 4);       // 4 MB
  float* part  = (float*)alloc((size_t)HEADS * BB * TP * EMB * 4); // 4 MB
  int*   idxb  = (int*)  alloc((size_t)BB * TP * VS * 4);
  float* wts   = (float*)alloc((size_t)BB * TP * VS * 4);
  int*   grand = (int*)  alloc((size_t)BB * TP * KMIX * GADD * 4);
  int*   rrand = (int*)  alloc((size_t)BB * TP * KMIX * RADD * 4);

  // 1. RNG + sel-row extraction (fused)
  init_kernel<<<dim3(BB * TP + 32), dim3(256), 0, stream>>>(x, xsel, grand, rrand);

  // 2. M_h = (Wq_h @ Wk_h^T) / 16   [8][256][256]
  gemm_nt<<<dim3(EMB / 64, EMB / 32, HEADS), dim3(256), 0, stream>>>(
      Wq, NQ, 256, Wk, NQ, 256, M8, EMB, (size_t)EMB * EMB, EMB, 0.0625f);

  // 3. PV_h = Wv_h @ Wu_h   [8][256][256]  (folds Wu into the value path)
  gemm_nn<<<dim3(EMB / 64, EMB / 32, HEADS), dim3(256), 0, stream>>>(
      Wv + 0, NQ, 256, Wu, EMB, (size_t)EMB * EMB, PV, EMB, (size_t)EMB * EMB, EMB);

  // 4. MLP hidden
  gemm_nn<<<dim3(HID / 64, (BB * TP) / 32, 1), dim3(256), 0, stream>>>(
      xsel, EMB, 0, W1, HID, 0, hid0, HID, 0, EMB);

  // 5. params (indices/weights)
  params2_kernel<<<dim3(BB * TP), dim3(256), 0, stream>>>(
      hid0, W1, b1, W2, b2, grand, rrand, idxb, wts);

  // 6. qk[bp, h] = xsel @ M_h
  gemm_nn<<<dim3(EMB / 64, (BB * TP) / 32, HEADS), dim3(256), 0, stream>>>(
      xsel, EMB, 0, M8, EMB, (size_t)EMB * EMB, qk, NQ, 256, EMB);

  // 7. fused attention (gather + dots + softmax + z)
  attn3_kernel<<<dim3(BB * TP), dim3(256), 0, stream>>>(
      x, qk, idxb, wts, zbuf);

  // 8. part_h = z_h @ PV_h
  gemm_nn<<<dim3(EMB / 64, (BB * TP) / 32, HEADS), dim3(256), 0, stream>>>(
      zbuf, NQ, 256, PV, EMB, (size_t)EMB * EMB, part, EMB, (size_t)BB * TP * EMB, EMB);

  // 9. final output (bu background + scatter-sum of head partials)
  final_out<<<dim3((BB * TT * EMB / 4) / 256), dim3(256), 0, stream>>>(
      part, bu, out);
}